// Round 4
// baseline (370.711 us; speedup 1.0000x reference)
//
#include <hip/hip_runtime.h>

typedef unsigned short u16;
typedef __attribute__((ext_vector_type(8))) _Float16 f16x8;
typedef __attribute__((ext_vector_type(2))) __fp16 fp16v2;
typedef __attribute__((ext_vector_type(4))) float f32x4;
typedef __attribute__((ext_vector_type(16))) float f32x16;

#define T_SEQ 2048
#define NH 16
#define DH 64
#define DM 1024
// NEG * log2(e), masks applied in log2 domain (softmax via exp2)
#define NEG2 (-14426.95f)
// 64^-0.25 * sqrt(log2(e)) : folded so S^T comes out pre-scaled for exp2
#define QS2 (0.42466089f)

__device__ __forceinline__ unsigned pk2(float a, float b) {
  union { fp16v2 v; unsigned u; } c;
  c.v = __builtin_amdgcn_cvt_pkrtz(a, b);
  return c.u;
}
__device__ __forceinline__ u16 f2h(float a) {
  union { _Float16 h; u16 u; } c; c.h = (_Float16)a; return c.u;
}

__device__ __forceinline__ void async_load16(const void* g, void* l) {
  __builtin_amdgcn_global_load_lds(
      (const __attribute__((address_space(1))) unsigned int*)(g),
      (__attribute__((address_space(3))) unsigned int*)(l), 16, 0, 0);
}

// ---------------- convert fp32 -> fp16 ----------------
__global__ __launch_bounds__(256) void convert_all(
    const float* __restrict__ q, const float* __restrict__ k, const float* __restrict__ v,
    const float* __restrict__ Wq, const float* __restrict__ Wk, const float* __restrict__ Wv,
    const float* __restrict__ Wo, u16* __restrict__ xb, u16* __restrict__ wb) {
  int blk = blockIdx.x;
  const float* src; u16* dst;
  if (blk < 12288) {
    int s = blk >> 12;
    src = (s == 0) ? q : (s == 1) ? k : v;
    dst = xb + (size_t)s * 8388608u;
    blk &= 4095;
  } else {
    int s = (blk - 12288) >> 9;
    src = (s == 0) ? Wq : (s == 1) ? Wk : (s == 2) ? Wv : Wo;
    dst = wb + (size_t)s * 1048576u;
    blk = (blk - 12288) & 511;
  }
  size_t base = (size_t)blk * 2048 + (size_t)threadIdx.x * 8;
  float4 a = *(const float4*)(src + base);
  float4 b2 = *(const float4*)(src + base + 4);
  uint4 st;
  st.x = pk2(a.x, a.y); st.y = pk2(a.z, a.w);
  st.z = pk2(b2.x, b2.y); st.w = pk2(b2.z, b2.w);
  *(uint4*)(dst + base) = st;
}

// ---------------- fused QKV projection GEMM (32x32x16 MFMA) ----------------
// which = n0>>10 selects INPUT activation (q/k/v at A+which*8M), weight, output.
// which<2 (Q/K): MFMA operands SWAPPED (row dim = channel); epilogue packs
//   along row, LDS-transposes, stores [bh][t][dh] coalesced (dwordx4).
// which==2 (V): normal order (row dim = t); stores VT [bh][dh][t] coalesced.
// K-loop: BK=32, THREE 16KB buffers, SINGLE barrier per iteration.
__global__ __launch_bounds__(256) void gemm_qkv(const u16* __restrict__ A,
                                                const u16* __restrict__ Wqb,
                                                const u16* __restrict__ Wkb,
                                                const u16* __restrict__ Wvb,
                                                u16* __restrict__ Qh, u16* __restrict__ Kh,
                                                u16* __restrict__ VTh) {
  __shared__ char lds[49152];  // 3 staging buffers of 16KB; epilogue tile aliases [0,33792)
  const int tid = threadIdx.x;
  const int wid = tid >> 6, lane = tid & 63;
  const int l32 = lane & 31, lh = lane >> 5;
  const int m0 = blockIdx.x * 128;
  const int n0 = blockIdx.y * 128;
  const int which = n0 >> 10;
  const int n0l = n0 & 1023;
  const u16* As = A + (size_t)which * 8388608u;
  const u16* Bw = (which == 0) ? Wqb : (which == 1) ? Wkb : Wvb;
  const int wm = wid >> 1, wn = wid & 1;
  f32x16 acc[2][2] = {};

  // cell c = mt*2+ks (1KB): M[m0+mt*32+l32][kt+ks*16+lh*8 ..+8]; wave stages mt=wid.
  const u16* gA = As + (size_t)(m0 + wid * 32 + l32) * 1024 + lh * 8;
  const u16* gB = Bw + (size_t)(n0l + wid * 32 + l32) * 1024 + lh * 8;
  // prologue: stage tiles 0,1 into buffers 0,1 (8 loads in flight per wave)
  for (int t = 0; t < 2; ++t) {
    char* bf = lds + t * 16384;
    async_load16(gA + t * 32, bf + (wid * 2 + 0) * 1024);
    async_load16(gA + t * 32 + 16, bf + (wid * 2 + 1) * 1024);
    async_load16(gB + t * 32, bf + 8192 + (wid * 2 + 0) * 1024);
    async_load16(gB + t * 32 + 16, bf + 8192 + (wid * 2 + 1) * 1024);
  }

  int buf = 0;
  for (int it = 0; it < 32; ++it) {
    // own tile-it loads landed; tile-(it+1) loads stay in flight
    if (it < 31) asm volatile("s_waitcnt vmcnt(4)" ::: "memory");
    else         asm volatile("s_waitcnt vmcnt(0)" ::: "memory");
    __builtin_amdgcn_s_barrier();   // all waves' tile-it loads landed; buf (it+2)%3 free
    asm volatile("" ::: "memory");  // pin LDS ops below the barrier
    char* cur = lds + buf * 16384;
    if (it < 30) {
      // prefetch tile it+2 into the buffer freed at iteration it-1
      char* nxt = lds + ((buf == 0) ? 2 : buf - 1) * 16384;
      int kt = (it + 2) * 32;
      async_load16(gA + kt, nxt + (wid * 2 + 0) * 1024);
      async_load16(gA + kt + 16, nxt + (wid * 2 + 1) * 1024);
      async_load16(gB + kt, nxt + 8192 + (wid * 2 + 0) * 1024);
      async_load16(gB + kt + 16, nxt + 8192 + (wid * 2 + 1) * 1024);
    }
    char* const rb = (which < 2) ? (cur + 8192) : cur;  // A-op: W for Q/K, X for V
    char* const cb = (which < 2) ? cur : (cur + 8192);
    // issue all 8 ds_reads (ks=0 group first), compute ks=0 under ks=1 reads
    f16x8 rf0[2], cf0[2], rf1[2], cf1[2];
    for (int i = 0; i < 2; ++i) {
      rf0[i] = *(const f16x8*)(rb + ((wm * 2 + i) * 2 + 0) * 1024 + lane * 16);
      cf0[i] = *(const f16x8*)(cb + ((wn * 2 + i) * 2 + 0) * 1024 + lane * 16);
    }
    for (int i = 0; i < 2; ++i) {
      rf1[i] = *(const f16x8*)(rb + ((wm * 2 + i) * 2 + 1) * 1024 + lane * 16);
      cf1[i] = *(const f16x8*)(cb + ((wn * 2 + i) * 2 + 1) * 1024 + lane * 16);
    }
    for (int i = 0; i < 2; ++i)
      for (int j = 0; j < 2; ++j)
        acc[i][j] = __builtin_amdgcn_mfma_f32_32x32x16_f16(rf0[i], cf0[j], acc[i][j], 0, 0, 0);
    for (int i = 0; i < 2; ++i)
      for (int j = 0; j < 2; ++j)
        acc[i][j] = __builtin_amdgcn_mfma_f32_32x32x16_f16(rf1[i], cf1[j], acc[i][j], 0, 0, 0);
    buf = (buf == 2) ? 0 : buf + 1;
  }

  // epilogue: C/D row = (reg&3)+8*(reg>>2)+4*lh, col = l32.
  // pack 4 consecutive rows (one reg group) -> uint2, LDS tile [col][row]
  const float s = (which < 2) ? QS2 : 1.0f;
  __syncthreads();  // full drain: all K-loop reads done before aliasing LDS
  for (int i = 0; i < 2; ++i)
    for (int j = 0; j < 2; ++j) {
      int colb = wn * 64 + j * 32 + l32;
      int rowb = wm * 64 + i * 32 + 4 * lh;
      for (int g = 0; g < 4; ++g) {
        uint2 pv;
        pv.x = pk2(acc[i][j][4 * g + 0] * s, acc[i][j][4 * g + 1] * s);
        pv.y = pk2(acc[i][j][4 * g + 2] * s, acc[i][j][4 * g + 3] * s);
        *(uint2*)(lds + colb * 264 + (rowb + 8 * g) * 2) = pv;
      }
    }
  __syncthreads();

  const int b = m0 >> 11, t0 = m0 & 2047, h0 = n0l >> 6;
  if (which < 2) {
    // LDS tile [t_local][channel]: rows = t (128), 256B of channels + pad
    u16* O = which ? Kh : Qh;
    for (int p = 0; p < 8; ++p) {
      int row = p * 16 + (tid >> 4);  // t_local
      int seg = tid & 15;
      uint4 val = *(const uint4*)(lds + row * 264 + seg * 16);
      int hl = seg >> 3, dh0 = (seg & 7) * 8;
      *(uint4*)(O + (((size_t)(b * NH + h0 + hl) * T_SEQ + t0 + row) << 6) + dh0) = val;
    }
  } else {
    // LDS tile [ch_local][t]: rows = channel (128), 256B of t + pad
    for (int p = 0; p < 8; ++p) {
      int row = p * 16 + (tid >> 4);  // ch_local
      int seg = tid & 15;
      uint4 val = *(const uint4*)(lds + row * 264 + seg * 16);
      int h = h0 + (row >> 6), dh = row & 63;
      *(uint4*)(VTh + (((size_t)(b * NH + h) * DH + dh) << 11) + t0 + seg * 8) = val;
    }
  }
}

// ---------------- output projection GEMM (32x32x16 MFMA, fp32 out) ----------------
// Same single-barrier / 3-buffer / split-lgkm K-loop as gemm_qkv.
__global__ __launch_bounds__(256) void gemm_out(const u16* __restrict__ A,
                                                const u16* __restrict__ Bw,
                                                float* __restrict__ O) {
  __shared__ char lds[49152];
  const int tid = threadIdx.x;
  const int wid = tid >> 6, lane = tid & 63;
  const int l32 = lane & 31, lh = lane >> 5;
  const int m0 = blockIdx.x * 128, n0 = blockIdx.y * 128;
  const int wm = wid >> 1, wn = wid & 1;
  f32x16 acc[2][2] = {};

  const u16* gA = A + (size_t)(m0 + wid * 32 + l32) * 1024 + lh * 8;
  const u16* gB = Bw + (size_t)(n0 + wid * 32 + l32) * 1024 + lh * 8;
  for (int t = 0; t < 2; ++t) {
    char* bf = lds + t * 16384;
    async_load16(gA + t * 32, bf + (wid * 2 + 0) * 1024);
    async_load16(gA + t * 32 + 16, bf + (wid * 2 + 1) * 1024);
    async_load16(gB + t * 32, bf + 8192 + (wid * 2 + 0) * 1024);
    async_load16(gB + t * 32 + 16, bf + 8192 + (wid * 2 + 1) * 1024);
  }

  int buf = 0;
  for (int it = 0; it < 32; ++it) {
    if (it < 31) asm volatile("s_waitcnt vmcnt(4)" ::: "memory");
    else         asm volatile("s_waitcnt vmcnt(0)" ::: "memory");
    __builtin_amdgcn_s_barrier();
    asm volatile("" ::: "memory");
    char* cur = lds + buf * 16384;
    if (it < 30) {
      char* nxt = lds + ((buf == 0) ? 2 : buf - 1) * 16384;
      int kt = (it + 2) * 32;
      async_load16(gA + kt, nxt + (wid * 2 + 0) * 1024);
      async_load16(gA + kt + 16, nxt + (wid * 2 + 1) * 1024);
      async_load16(gB + kt, nxt + 8192 + (wid * 2 + 0) * 1024);
      async_load16(gB + kt + 16, nxt + 8192 + (wid * 2 + 1) * 1024);
    }
    f16x8 af0[2], bf0[2], af1[2], bf1[2];
    for (int i = 0; i < 2; ++i) {
      af0[i] = *(const f16x8*)(cur + ((wm * 2 + i) * 2 + 0) * 1024 + lane * 16);
      bf0[i] = *(const f16x8*)(cur + 8192 + ((wn * 2 + i) * 2 + 0) * 1024 + lane * 16);
    }
    for (int i = 0; i < 2; ++i) {
      af1[i] = *(const f16x8*)(cur + ((wm * 2 + i) * 2 + 1) * 1024 + lane * 16);
      bf1[i] = *(const f16x8*)(cur + 8192 + ((wn * 2 + i) * 2 + 1) * 1024 + lane * 16);
    }
    for (int i = 0; i < 2; ++i)
      for (int j = 0; j < 2; ++j)
        acc[i][j] = __builtin_amdgcn_mfma_f32_32x32x16_f16(af0[i], bf0[j], acc[i][j], 0, 0, 0);
    for (int i = 0; i < 2; ++i)
      for (int j = 0; j < 2; ++j)
        acc[i][j] = __builtin_amdgcn_mfma_f32_32x32x16_f16(af1[i], bf1[j], acc[i][j], 0, 0, 0);
    buf = (buf == 2) ? 0 : buf + 1;
  }
  for (int i = 0; i < 2; ++i)
    for (int j = 0; j < 2; ++j) {
      int col = n0 + wn * 64 + j * 32 + l32;
      int rowb = m0 + wm * 64 + i * 32 + 4 * lh;
      for (int g = 0; g < 4; ++g)
        for (int rr = 0; rr < 4; ++rr)
          O[(size_t)(rowb + 8 * g + rr) * 1024 + col] = acc[i][j][4 * g + rr];
    }
}

// ---------------- Flash attention (S^T formulation, fp16, 8 waves) ----------------
// Qh/Kh: f16 [bh][t][64] pre-scaled by QS2. VTh: f16 [bh][dh][t].
// ctx out: f16 [b][t][1024]. Block = 512 thr, q-tile 128; pair (p8, 15-p8).
// XCD swizzle: bid = p8*64 + bh  ->  same-head blocks share XCD (bid&7 = bh&7).
// K/V chunks DOUBLE-BUFFERED with depth-1 prefetch: ONE s_barrier per chunk;
// chunk c+1's global_load_lds issued right after barrier(c) so its latency
// hides under chunk c's full compute (~2500 cyc >> ~900 cyc HBM). Safety:
// a wave passing barrier(c) has finished all chunk-(c-1) reads, so
// buf[(c+1)&1] == buf[(c-1)&1] is free when the prefetch issues. vmcnt(0)
// at chunk top covers only this wave's own chunk-c loads (issued one full
// chunk earlier -> ~free in steady state).
__global__ __launch_bounds__(512) void attn_kernel(const u16* __restrict__ Qh,
                                                   const u16* __restrict__ Kh,
                                                   const u16* __restrict__ VTh,
                                                   const float* __restrict__ attn_mask,
                                                   const int* __restrict__ mfp,
                                                   u16* __restrict__ ctx) {
  __shared__ char kls[2][8192];   // K chunk (64s x 64k), cells (st*2+kk), x2 dbuf
  __shared__ char vls[2][8192];   // V^T chunk (64dh x 64s), cells (nt*2+kk), x2 dbuf
  __shared__ char pls[8][2048];   // per-wave P (16q x 64s) in A-frag order
  __shared__ float maskb[T_SEQ];  // pad bias in log2 domain
  __shared__ int mzf;             // 1 if any pad-mask zero for this b

  const int tid = threadIdx.x;
  const int wid = tid >> 6, lane = tid & 63;
  const int lm = lane & 15, lq = lane >> 4;
  const int bid = blockIdx.x;
  const int bh_i = bid & 63, p8 = bid >> 6;
  const int b = bh_i >> 4, h = bh_i & 15;
  const int mf = *mfp;
  const size_t bh = (size_t)(b * NH + h);
  const u16* Qbh = Qh + bh * T_SEQ * DH;
  const u16* Kbh = Kh + bh * T_SEQ * DH;
  const u16* VTbh = VTh + bh * DH * T_SEQ;

  if (tid == 0) mzf = 0;
  __syncthreads();
  {
    int az = 0;
    for (int i = tid; i < T_SEQ; i += 512) {
      float mv = attn_mask[(size_t)b * T_SEQ + i];
      maskb[i] = (mv == 0.0f) ? NEG2 : 0.0f;
      az |= (mv == 0.0f);
    }
    if (az) mzf = 1;  // benign same-value race
  }
  __syncthreads();
  const int maskzero = mzf;

  for (int half = 0; half < 2; ++half) {
    const int qt = half ? (15 - p8) : p8;   // 128-row q-tile index
    const int q0 = qt * 128;
    const int qw = q0 + wid * 16;
    // Q as B-operand: lane needs Q[q=qw+lm][k=kk*32+lq*8+j]
    f16x8 qf[2];
    qf[0] = *(const f16x8*)(Qbh + (size_t)(qw + lm) * DH + lq * 8);
    qf[1] = *(const f16x8*)(Qbh + (size_t)(qw + lm) * DH + 32 + lq * 8);

    f32x4 acc[4] = {};                // O: row=q_loc(lq*4+r), col=dh(nt*16+lm)
    float mprev = -1e30f, lsum = 0.f; // state for q = qw+lm (replicated over lq)

    const int nch = mf ? (qt + 1) * 2 : 32;
    // all waves done with previous half's reads; prefetch chunk 0 into buf0
    __syncthreads();
    {
      async_load16(Kbh + (size_t)((wid >> 1) * 16 + lm) * DH + (wid & 1) * 32 + lq * 8,
                   kls[0] + wid * 1024);
      async_load16(VTbh + (size_t)((wid >> 1) * 16 + lm) * T_SEQ + (wid & 1) * 32 + lq * 8,
                   vls[0] + wid * 1024);
    }
    for (int c = 0; c < nch; ++c) {
      const int s0 = c * 64;
      // own chunk-c loads landed (issued one chunk ago)
      asm volatile("s_waitcnt vmcnt(0)" ::: "memory");
      __builtin_amdgcn_s_barrier();   // all waves' chunk-c loads landed;
                                      // buf[(c+1)&1] free (chunk c-1 reads done)
      asm volatile("" ::: "memory");
      if (c + 1 < nch) {
        const int s1 = s0 + 64;
        async_load16(Kbh + (size_t)(s1 + (wid >> 1) * 16 + lm) * DH + (wid & 1) * 32 + lq * 8,
                     kls[(c + 1) & 1] + wid * 1024);
        async_load16(VTbh + (size_t)((wid >> 1) * 16 + lm) * T_SEQ + s1 + (wid & 1) * 32 + lq * 8,
                     vls[(c + 1) & 1] + wid * 1024);
      }
      const char* kcur = kls[c & 1];
      const char* vcur = vls[c & 1];

      // S^T tiles: A=K (m=s), B=Q (n=q). sc[st]: row s_loc=lq*4+r, col q=qw+lm
      f32x4 sc[4];
      for (int st = 0; st < 4; ++st) {
        f32x4 z = {0.f, 0.f, 0.f, 0.f};
        sc[st] = z;
        for (int kk = 0; kk < 2; ++kk) {
          f16x8 kf = *(const f16x8*)(kcur + ((st * 2 + kk) * 64 + lane) * 16);
          sc[st] = __builtin_amdgcn_mfma_f32_16x16x32_f16(kf, qf[kk], sc[st], 0, 0, 0);
        }
      }
      // pad bias only when the mask actually has zeros (wave-uniform skip)
      if (maskzero) {
        for (int st = 0; st < 4; ++st) {
          f32x4 mb = *(const f32x4*)(maskb + s0 + st * 16 + lq * 4);
          for (int r = 0; r < 4; ++r) sc[st][r] += mb[r];
        }
      }
      // causal: only diagonal-overlapping chunks need the compare
      if (mf && (s0 + 64 > qw)) {
        int qg = qw + lm;
        for (int st = 0; st < 4; ++st)
          for (int r = 0; r < 4; ++r)
            if (s0 + st * 16 + lq * 4 + r > qg) sc[st][r] = NEG2;
      }
      // online softmax over s: chunk max, then conditional rescale
      float mx = fmaxf(fmaxf(sc[0][0], sc[0][1]), fmaxf(sc[0][2], sc[0][3]));
      for (int st = 1; st < 4; ++st) {
        float t2 = fmaxf(fmaxf(sc[st][0], sc[st][1]), fmaxf(sc[st][2], sc[st][3]));
        mx = fmaxf(mx, t2);
      }
      mx = fmaxf(mx, __shfl_xor(mx, 16));
      mx = fmaxf(mx, __shfl_xor(mx, 32));
      float mn = mprev;
      if (__ballot(mx > mprev) != 0ull) {  // wave-uniform: any row's max grew
        mn = fmaxf(mprev, mx);
        float alpha = exp2f(mprev - mn);
        for (int r = 0; r < 4; ++r) {
          float ar = __shfl(alpha, lq * 4 + r);
          for (int nt = 0; nt < 4; ++nt) acc[nt][r] *= ar;
        }
        lsum *= alpha;
        mprev = mn;
      }
      float ps = 0.f;
      for (int st = 0; st < 4; ++st)
        for (int r = 0; r < 4; ++r) {
          float p = exp2f(sc[st][r] - mn);
          sc[st][r] = p;
          ps += p;
        }
      ps += __shfl_xor(ps, 16);
      ps += __shfl_xor(ps, 32);
      lsum += ps;
      // P -> per-wave LDS in A-frag order (packed b64 writes, pkrtz)
      {
        char* pw = pls[wid];
        for (int st = 0; st < 4; ++st) {
          int kk = st >> 1;
          int lqp = (st & 1) * 2 + (lq >> 1);
          uint2 pv;
          pv.x = pk2(sc[st][0], sc[st][1]);
          pv.y = pk2(sc[st][2], sc[st][3]);
          *(uint2*)(pw + kk * 1024 + (lqp * 16 + lm) * 16 + (lq & 1) * 8) = pv;
        }
      }
      asm volatile("s_waitcnt lgkmcnt(0)" ::: "memory");
      for (int kk = 0; kk < 2; ++kk) {
        f16x8 pf = *(const f16x8*)(pls[wid] + kk * 1024 + lane * 16);
        for (int nt = 0; nt < 4; ++nt) {
          f16x8 vf = *(const f16x8*)(vcur + ((nt * 2 + kk) * 64 + lane) * 16);
          acc[nt] = __builtin_amdgcn_mfma_f32_16x16x32_f16(pf, vf, acc[nt], 0, 0, 0);
        }
      }
    }
    // epilogue: ctx[b][t][h*64+dh] f16
    float inv = 1.0f / lsum;
    for (int r = 0; r < 4; ++r) {
      float ir = __shfl(inv, lq * 4 + r);
      int t = qw + lq * 4 + r;
      for (int nt = 0; nt < 4; ++nt)
        ctx[((size_t)(b * T_SEQ + t) * DM) + h * DH + nt * 16 + lm] = f2h(acc[nt][r] * ir);
    }
  }
}

extern "C" void kernel_launch(void* const* d_in, const int* in_sizes, int n_in,
                              void* d_out, int out_size, void* d_ws, size_t ws_size,
                              hipStream_t stream) {
  const float* q = (const float*)d_in[0];
  const float* k = (const float*)d_in[1];
  const float* v = (const float*)d_in[2];
  const float* attn_mask = (const float*)d_in[3];
  const float* Wq = (const float*)d_in[4];
  const float* Wk = (const float*)d_in[5];
  const float* Wv = (const float*)d_in[6];
  const float* Wo = (const float*)d_in[7];
  const int* mf = (const int*)d_in[8];

  u16* ws = (u16*)d_ws;
  u16* qb  = ws;                      // f16 inputs [8192,1024] x3 (q,k,v contiguous)
  u16* wqb = ws + 3u * 8388608u;      // f16 weights x4
  u16* wkb = wqb + 1048576u;
  u16* wvb = wkb + 1048576u;
  u16* wob = wvb + 1048576u;
  u16* Qh  = wob + 1048576u;          // [bh][t][64]
  u16* Kh  = Qh + 8388608u;           // [bh][t][64]
  u16* VTh = Kh + 8388608u;           // [bh][dh][2048]
  u16* ctxb = ws;                     // alias over qb (dead after projections)

  convert_all<<<14336, 256, 0, stream>>>(q, k, v, Wq, Wk, Wv, Wo, qb, wqb);

  dim3 gq(64, 24);
  gemm_qkv<<<gq, 256, 0, stream>>>(qb, wqb, wkb, wvb, Qh, Kh, VTh);

  attn_kernel<<<512, 512, 0, stream>>>(Qh, Kh, VTh, attn_mask, mf, ctxb);

  dim3 gg(64, 8);
  gemm_out<<<gg, 256, 0, stream>>>(ctxb, wob, (float*)d_out);
}

// Round 5
// 359.509 us; speedup vs baseline: 1.0312x; 1.0312x over previous
//
#include <hip/hip_runtime.h>

typedef unsigned short u16;
typedef __attribute__((ext_vector_type(8))) _Float16 f16x8;
typedef __attribute__((ext_vector_type(2))) __fp16 fp16v2;
typedef __attribute__((ext_vector_type(4))) float f32x4;
typedef __attribute__((ext_vector_type(16))) float f32x16;

#define T_SEQ 2048
#define NH 16
#define DH 64
#define DM 1024
// NEG * log2(e), masks applied in log2 domain (softmax via exp2)
#define NEG2 (-14426.95f)
// 64^-0.25 * sqrt(log2(e)) : folded so S^T comes out pre-scaled for exp2
#define QS2 (0.42466089f)

__device__ __forceinline__ unsigned pk2(float a, float b) {
  union { fp16v2 v; unsigned u; } c;
  c.v = __builtin_amdgcn_cvt_pkrtz(a, b);
  return c.u;
}
__device__ __forceinline__ u16 f2h(float a) {
  union { _Float16 h; u16 u; } c; c.h = (_Float16)a; return c.u;
}

__device__ __forceinline__ void async_load16(const void* g, void* l) {
  __builtin_amdgcn_global_load_lds(
      (const __attribute__((address_space(1))) unsigned int*)(g),
      (__attribute__((address_space(3))) unsigned int*)(l), 16, 0, 0);
}

// ---------------- convert fp32 -> fp16 ----------------
__global__ __launch_bounds__(256) void convert_all(
    const float* __restrict__ q, const float* __restrict__ k, const float* __restrict__ v,
    const float* __restrict__ Wq, const float* __restrict__ Wk, const float* __restrict__ Wv,
    const float* __restrict__ Wo, u16* __restrict__ xb, u16* __restrict__ wb) {
  int blk = blockIdx.x;
  const float* src; u16* dst;
  if (blk < 12288) {
    int s = blk >> 12;
    src = (s == 0) ? q : (s == 1) ? k : v;
    dst = xb + (size_t)s * 8388608u;
    blk &= 4095;
  } else {
    int s = (blk - 12288) >> 9;
    src = (s == 0) ? Wq : (s == 1) ? Wk : (s == 2) ? Wv : Wo;
    dst = wb + (size_t)s * 1048576u;
    blk = (blk - 12288) & 511;
  }
  size_t base = (size_t)blk * 2048 + (size_t)threadIdx.x * 8;
  float4 a = *(const float4*)(src + base);
  float4 b2 = *(const float4*)(src + base + 4);
  uint4 st;
  st.x = pk2(a.x, a.y); st.y = pk2(a.z, a.w);
  st.z = pk2(b2.x, b2.y); st.w = pk2(b2.z, b2.w);
  *(uint4*)(dst + base) = st;
}

// ---------------- fused QKV projection GEMM: 256x128 tile, phase-split, counted vmcnt ----
// which = by>>3 selects input activation/weight/output. BM=256 (t), BN=128 (ch), BK=64.
// 8 waves (512 thr). which<2 (Q/K): MFMA operands SWAPPED (acc rows = channel);
// which==2 (V): acc rows = t. Per-wave 64x64 via 2x2 of 32x32x16 MFMA, 4 k-steps.
// LDS: 3 buffers x 48KB (X-tile 32KB = cells 0..31, W-tile 16KB = cells 32..47),
// cell = 1KB [l32][lh] (rows 32 x 16 u16), staged by 6 gload_lds/wave/K-tile.
// Schedule per K-tile (2 phases):
//   A: ds_read a0/b0/b1 (12 b128, bufc) | stage chunk0 tile kt+2 -> bufn |
//      barrier | lgkmcnt(0)+sched_barrier | setprio1 | 8 MFMA | setprio0 | barrier
//   B: ds_read a1 (4) | stage chunk1 | vmcnt(6) [tile kt+1 landed; kt+2's 6 stay
//      in flight -- never drains to 0] | barrier | ... | 8 MFMA | ... | barrier
// Safety: stage target bufn=(kt+2)%3 was fully read at tile kt-1, whose reads
// retired before B(kt-1)'s trailing barrier (same invariant as the proven
// tri-buffer loop). vmcnt(6): outstanding = {kt+1:6, kt+2:6}; keep 6 newest.
__global__ __launch_bounds__(512) void gemm_qkv(const u16* __restrict__ A,
                                                const u16* __restrict__ Wqb,
                                                const u16* __restrict__ Wkb,
                                                const u16* __restrict__ Wvb,
                                                u16* __restrict__ Qh, u16* __restrict__ Kh,
                                                u16* __restrict__ VTh) {
  __shared__ char lds[147456];  // 3 x 48KB staging; epilogue tile aliases [0, ~68KB)
  const int tid = threadIdx.x;
  const int wid = tid >> 6, lane = tid & 63;
  const int l32 = lane & 31, lh = lane >> 5;
  const int m0 = blockIdx.x * 256;               // t rows
  const int n0 = blockIdx.y * 128;               // ch cols + which
  const int which = n0 >> 10;
  const int n0l = n0 & 1023;
  const u16* As = A + (size_t)which * 8388608u;
  const u16* Bw = (which == 0) ? Wqb : (which == 1) ? Wkb : Wvb;
  f32x16 acc[2][2] = {};

  // staging sources: cell c = wid*6+u. c<32: X rows m0+(c>>2)*32+l32;
  // c>=32: W rows n0l+((c-32)>>2)*32+l32. col base = (c&3)*16 + lh*8 (+kt*64).
  const u16* gsrc[6]; int ldso[6];
#pragma unroll
  for (int u = 0; u < 6; ++u) {
    int c = wid * 6 + u;
    ldso[u] = c * 1024;
    if (c < 32)
      gsrc[u] = As + (size_t)(m0 + (c >> 2) * 32 + l32) * 1024 + (c & 3) * 16 + lh * 8;
    else {
      int cw = c - 32;
      gsrc[u] = Bw + (size_t)(n0l + (cw >> 2) * 32 + l32) * 1024 + (cw & 3) * 16 + lh * 8;
    }
  }

  // fragment addressing: rb = MFMA A-operand region, cb = B-operand region
  const int rOff = (which < 2) ? 32768 : 0;   // Q/K: rows = W; V: rows = X
  const int cOff = 32768 - rOff;
  const int rgo = (which < 2) ? ((wid & 1) * 2) : ((wid >> 1) * 2);  // row-group base
  const int cgo = (which < 2) ? ((wid >> 1) * 2) : ((wid & 1) * 2);  // col-group base

  // prologue: stage tiles 0,1 fully (12 loads/wave in flight), wait oldest 6
#pragma unroll
  for (int u = 0; u < 6; ++u) async_load16(gsrc[u] + 0 * 64, lds + 0 * 49152 + ldso[u]);
#pragma unroll
  for (int u = 0; u < 6; ++u) async_load16(gsrc[u] + 1 * 64, lds + 1 * 49152 + ldso[u]);
  asm volatile("s_waitcnt vmcnt(6)" ::: "memory");
  __builtin_amdgcn_s_barrier();
  asm volatile("" ::: "memory");

  int slotc = 0, slotn = 2;
  for (int kt = 0; kt < 16; ++kt) {
    char* bufc = lds + slotc * 49152;
    char* bufn = lds + slotn * 49152;
    const char* rb = bufc + rOff;
    const char* cb = bufc + cOff;
    f16x8 a0[4], a1[4], b0[4], b1[4];
    // ---- Phase A ----
#pragma unroll
    for (int k = 0; k < 4; ++k) {
      a0[k] = *(const f16x8*)(rb + ((rgo + 0) * 4 + k) * 1024 + lane * 16);
      b0[k] = *(const f16x8*)(cb + ((cgo + 0) * 4 + k) * 1024 + lane * 16);
      b1[k] = *(const f16x8*)(cb + ((cgo + 1) * 4 + k) * 1024 + lane * 16);
    }
    if (kt < 14) {
#pragma unroll
      for (int u = 0; u < 3; ++u) async_load16(gsrc[u] + (kt + 2) * 64, bufn + ldso[u]);
    }
    asm volatile("" ::: "memory");
    __builtin_amdgcn_s_barrier();
    asm volatile("s_waitcnt lgkmcnt(0)" ::: "memory");
    __builtin_amdgcn_sched_barrier(0);
    __builtin_amdgcn_s_setprio(1);
#pragma unroll
    for (int k = 0; k < 4; ++k) {
      acc[0][0] = __builtin_amdgcn_mfma_f32_32x32x16_f16(a0[k], b0[k], acc[0][0], 0, 0, 0);
      acc[0][1] = __builtin_amdgcn_mfma_f32_32x32x16_f16(a0[k], b1[k], acc[0][1], 0, 0, 0);
    }
    __builtin_amdgcn_s_setprio(0);
    asm volatile("" ::: "memory");
    __builtin_amdgcn_s_barrier();
    // ---- Phase B ----
#pragma unroll
    for (int k = 0; k < 4; ++k)
      a1[k] = *(const f16x8*)(rb + ((rgo + 1) * 4 + k) * 1024 + lane * 16);
    if (kt < 14) {
#pragma unroll
      for (int u = 3; u < 6; ++u) async_load16(gsrc[u] + (kt + 2) * 64, bufn + ldso[u]);
    }
    if (kt < 14) asm volatile("s_waitcnt vmcnt(6)" ::: "memory");
    else         asm volatile("s_waitcnt vmcnt(0)" ::: "memory");
    asm volatile("" ::: "memory");
    __builtin_amdgcn_s_barrier();
    asm volatile("s_waitcnt lgkmcnt(0)" ::: "memory");
    __builtin_amdgcn_sched_barrier(0);
    __builtin_amdgcn_s_setprio(1);
#pragma unroll
    for (int k = 0; k < 4; ++k) {
      acc[1][0] = __builtin_amdgcn_mfma_f32_32x32x16_f16(a1[k], b0[k], acc[1][0], 0, 0, 0);
      acc[1][1] = __builtin_amdgcn_mfma_f32_32x32x16_f16(a1[k], b1[k], acc[1][1], 0, 0, 0);
    }
    __builtin_amdgcn_s_setprio(0);
    asm volatile("" ::: "memory");
    __builtin_amdgcn_s_barrier();
    slotc = (slotc == 2) ? 0 : slotc + 1;
    slotn = (slotn == 2) ? 0 : slotn + 1;
  }

  // epilogue. C/D 32x32: col = l32, row = (reg&3)+8*(reg>>2)+4*lh.
  const float s = (which < 2) ? QS2 : 1.0f;
  const int b = m0 >> 11, t0 = m0 & 2047, h0 = n0l >> 6;
  __syncthreads();  // full drain before aliasing staging LDS
  if (which < 2) {
    // acc rows = ch (128), cols = t (256). LDS tile [t 256][ch 264B pitch]
#pragma unroll
    for (int i = 0; i < 2; ++i)
#pragma unroll
      for (int j = 0; j < 2; ++j) {
        int colb = (wid >> 1) * 64 + j * 32 + l32;   // t_local
        int rowb = (wid & 1) * 64 + i * 32 + 4 * lh; // ch base
#pragma unroll
        for (int g = 0; g < 4; ++g) {
          uint2 pv;
          pv.x = pk2(acc[i][j][4 * g + 0] * s, acc[i][j][4 * g + 1] * s);
          pv.y = pk2(acc[i][j][4 * g + 2] * s, acc[i][j][4 * g + 3] * s);
          *(uint2*)(lds + colb * 264 + (rowb + 8 * g) * 2) = pv;
        }
      }
    __syncthreads();
    u16* O = which ? Kh : Qh;
#pragma unroll
    for (int p = 0; p < 8; ++p) {
      int row = p * 32 + (tid >> 4);  // t_local 0..255
      int seg = tid & 15;
      uint4 val = *(const uint4*)(lds + row * 264 + seg * 16);
      int hl = seg >> 3, dh0 = (seg & 7) * 8;
      *(uint4*)(O + (((size_t)(b * NH + h0 + hl) * T_SEQ + t0 + row) << 6) + dh0) = val;
    }
  } else {
    // acc rows = t (256), cols = ch (128). LDS tile [ch 128][t 520B pitch]
#pragma unroll
    for (int i = 0; i < 2; ++i)
#pragma unroll
      for (int j = 0; j < 2; ++j) {
        int colb = (wid & 1) * 64 + j * 32 + l32;    // ch_local
        int rowb = (wid >> 1) * 64 + i * 32 + 4 * lh; // t base
#pragma unroll
        for (int g = 0; g < 4; ++g) {
          uint2 pv;
          pv.x = pk2(acc[i][j][4 * g + 0], acc[i][j][4 * g + 1]);
          pv.y = pk2(acc[i][j][4 * g + 2], acc[i][j][4 * g + 3]);
          *(uint2*)(lds + colb * 520 + (rowb + 8 * g) * 2) = pv;
        }
      }
    __syncthreads();
#pragma unroll
    for (int p = 0; p < 8; ++p) {
      int row = p * 16 + (tid >> 5);  // ch_local 0..127
      int seg = tid & 31;
      uint4 val = *(const uint4*)(lds + row * 520 + seg * 16);
      int h = h0 + (row >> 6), dh = row & 63;
      *(uint4*)(VTh + (((size_t)(b * NH + h) * DH + dh) << 11) + t0 + seg * 8) = val;
    }
  }
}

// ---------------- output projection GEMM (32x32x16 MFMA, fp32 out) ----------------
// Single-barrier / 3-buffer / split-lgkm K-loop (unchanged this round).
__global__ __launch_bounds__(256) void gemm_out(const u16* __restrict__ A,
                                                const u16* __restrict__ Bw,
                                                float* __restrict__ O) {
  __shared__ char lds[49152];
  const int tid = threadIdx.x;
  const int wid = tid >> 6, lane = tid & 63;
  const int l32 = lane & 31, lh = lane >> 5;
  const int m0 = blockIdx.x * 128, n0 = blockIdx.y * 128;
  const int wm = wid >> 1, wn = wid & 1;
  f32x16 acc[2][2] = {};

  const u16* gA = A + (size_t)(m0 + wid * 32 + l32) * 1024 + lh * 8;
  const u16* gB = Bw + (size_t)(n0 + wid * 32 + l32) * 1024 + lh * 8;
  for (int t = 0; t < 2; ++t) {
    char* bf = lds + t * 16384;
    async_load16(gA + t * 32, bf + (wid * 2 + 0) * 1024);
    async_load16(gA + t * 32 + 16, bf + (wid * 2 + 1) * 1024);
    async_load16(gB + t * 32, bf + 8192 + (wid * 2 + 0) * 1024);
    async_load16(gB + t * 32 + 16, bf + 8192 + (wid * 2 + 1) * 1024);
  }

  int buf = 0;
  for (int it = 0; it < 32; ++it) {
    if (it < 31) asm volatile("s_waitcnt vmcnt(4)" ::: "memory");
    else         asm volatile("s_waitcnt vmcnt(0)" ::: "memory");
    __builtin_amdgcn_s_barrier();
    asm volatile("" ::: "memory");
    char* cur = lds + buf * 16384;
    if (it < 30) {
      char* nxt = lds + ((buf == 0) ? 2 : buf - 1) * 16384;
      int kt = (it + 2) * 32;
      async_load16(gA + kt, nxt + (wid * 2 + 0) * 1024);
      async_load16(gA + kt + 16, nxt + (wid * 2 + 1) * 1024);
      async_load16(gB + kt, nxt + 8192 + (wid * 2 + 0) * 1024);
      async_load16(gB + kt + 16, nxt + 8192 + (wid * 2 + 1) * 1024);
    }
    f16x8 af0[2], bf0[2], af1[2], bf1[2];
    for (int i = 0; i < 2; ++i) {
      af0[i] = *(const f16x8*)(cur + ((wm * 2 + i) * 2 + 0) * 1024 + lane * 16);
      bf0[i] = *(const f16x8*)(cur + 8192 + ((wn * 2 + i) * 2 + 0) * 1024 + lane * 16);
    }
    for (int i = 0; i < 2; ++i) {
      af1[i] = *(const f16x8*)(cur + ((wm * 2 + i) * 2 + 1) * 1024 + lane * 16);
      bf1[i] = *(const f16x8*)(cur + 8192 + ((wn * 2 + i) * 2 + 1) * 1024 + lane * 16);
    }
    for (int i = 0; i < 2; ++i)
      for (int j = 0; j < 2; ++j)
        acc[i][j] = __builtin_amdgcn_mfma_f32_32x32x16_f16(af0[i], bf0[j], acc[i][j], 0, 0, 0);
    for (int i = 0; i < 2; ++i)
      for (int j = 0; j < 2; ++j)
        acc[i][j] = __builtin_amdgcn_mfma_f32_32x32x16_f16(af1[i], bf1[j], acc[i][j], 0, 0, 0);
    buf = (buf == 2) ? 0 : buf + 1;
  }
  for (int i = 0; i < 2; ++i)
    for (int j = 0; j < 2; ++j) {
      int col = n0 + wn * 64 + j * 32 + l32;
      int rowb = m0 + wm * 64 + i * 32 + 4 * lh;
      for (int g = 0; g < 4; ++g)
        for (int rr = 0; rr < 4; ++rr)
          O[(size_t)(rowb + 8 * g + rr) * 1024 + col] = acc[i][j][4 * g + rr];
    }
}

// ---------------- Flash attention (S^T formulation, fp16, 8 waves) ----------------
// Unchanged from round 4 (passing): K/V chunks double-buffered, depth-1 prefetch,
// one s_barrier per chunk.
__global__ __launch_bounds__(512) void attn_kernel(const u16* __restrict__ Qh,
                                                   const u16* __restrict__ Kh,
                                                   const u16* __restrict__ VTh,
                                                   const float* __restrict__ attn_mask,
                                                   const int* __restrict__ mfp,
                                                   u16* __restrict__ ctx) {
  __shared__ char kls[2][8192];   // K chunk (64s x 64k), cells (st*2+kk), x2 dbuf
  __shared__ char vls[2][8192];   // V^T chunk (64dh x 64s), cells (nt*2+kk), x2 dbuf
  __shared__ char pls[8][2048];   // per-wave P (16q x 64s) in A-frag order
  __shared__ float maskb[T_SEQ];  // pad bias in log2 domain
  __shared__ int mzf;             // 1 if any pad-mask zero for this b

  const int tid = threadIdx.x;
  const int wid = tid >> 6, lane = tid & 63;
  const int lm = lane & 15, lq = lane >> 4;
  const int bid = blockIdx.x;
  const int bh_i = bid & 63, p8 = bid >> 6;
  const int b = bh_i >> 4, h = bh_i & 15;
  const int mf = *mfp;
  const size_t bh = (size_t)(b * NH + h);
  const u16* Qbh = Qh + bh * T_SEQ * DH;
  const u16* Kbh = Kh + bh * T_SEQ * DH;
  const u16* VTbh = VTh + bh * DH * T_SEQ;

  if (tid == 0) mzf = 0;
  __syncthreads();
  {
    int az = 0;
    for (int i = tid; i < T_SEQ; i += 512) {
      float mv = attn_mask[(size_t)b * T_SEQ + i];
      maskb[i] = (mv == 0.0f) ? NEG2 : 0.0f;
      az |= (mv == 0.0f);
    }
    if (az) mzf = 1;  // benign same-value race
  }
  __syncthreads();
  const int maskzero = mzf;

  for (int half = 0; half < 2; ++half) {
    const int qt = half ? (15 - p8) : p8;   // 128-row q-tile index
    const int q0 = qt * 128;
    const int qw = q0 + wid * 16;
    f16x8 qf[2];
    qf[0] = *(const f16x8*)(Qbh + (size_t)(qw + lm) * DH + lq * 8);
    qf[1] = *(const f16x8*)(Qbh + (size_t)(qw + lm) * DH + 32 + lq * 8);

    f32x4 acc[4] = {};
    float mprev = -1e30f, lsum = 0.f;

    const int nch = mf ? (qt + 1) * 2 : 32;
    __syncthreads();
    {
      async_load16(Kbh + (size_t)((wid >> 1) * 16 + lm) * DH + (wid & 1) * 32 + lq * 8,
                   kls[0] + wid * 1024);
      async_load16(VTbh + (size_t)((wid >> 1) * 16 + lm) * T_SEQ + (wid & 1) * 32 + lq * 8,
                   vls[0] + wid * 1024);
    }
    for (int c = 0; c < nch; ++c) {
      const int s0 = c * 64;
      asm volatile("s_waitcnt vmcnt(0)" ::: "memory");
      __builtin_amdgcn_s_barrier();
      asm volatile("" ::: "memory");
      if (c + 1 < nch) {
        const int s1 = s0 + 64;
        async_load16(Kbh + (size_t)(s1 + (wid >> 1) * 16 + lm) * DH + (wid & 1) * 32 + lq * 8,
                     kls[(c + 1) & 1] + wid * 1024);
        async_load16(VTbh + (size_t)((wid >> 1) * 16 + lm) * T_SEQ + s1 + (wid & 1) * 32 + lq * 8,
                     vls[(c + 1) & 1] + wid * 1024);
      }
      const char* kcur = kls[c & 1];
      const char* vcur = vls[c & 1];

      f32x4 sc[4];
      for (int st = 0; st < 4; ++st) {
        f32x4 z = {0.f, 0.f, 0.f, 0.f};
        sc[st] = z;
        for (int kk = 0; kk < 2; ++kk) {
          f16x8 kf = *(const f16x8*)(kcur + ((st * 2 + kk) * 64 + lane) * 16);
          sc[st] = __builtin_amdgcn_mfma_f32_16x16x32_f16(kf, qf[kk], sc[st], 0, 0, 0);
        }
      }
      if (maskzero) {
        for (int st = 0; st < 4; ++st) {
          f32x4 mb = *(const f32x4*)(maskb + s0 + st * 16 + lq * 4);
          for (int r = 0; r < 4; ++r) sc[st][r] += mb[r];
        }
      }
      if (mf && (s0 + 64 > qw)) {
        int qg = qw + lm;
        for (int st = 0; st < 4; ++st)
          for (int r = 0; r < 4; ++r)
            if (s0 + st * 16 + lq * 4 + r > qg) sc[st][r] = NEG2;
      }
      float mx = fmaxf(fmaxf(sc[0][0], sc[0][1]), fmaxf(sc[0][2], sc[0][3]));
      for (int st = 1; st < 4; ++st) {
        float t2 = fmaxf(fmaxf(sc[st][0], sc[st][1]), fmaxf(sc[st][2], sc[st][3]));
        mx = fmaxf(mx, t2);
      }
      mx = fmaxf(mx, __shfl_xor(mx, 16));
      mx = fmaxf(mx, __shfl_xor(mx, 32));
      float mn = mprev;
      if (__ballot(mx > mprev) != 0ull) {
        mn = fmaxf(mprev, mx);
        float alpha = exp2f(mprev - mn);
        for (int r = 0; r < 4; ++r) {
          float ar = __shfl(alpha, lq * 4 + r);
          for (int nt = 0; nt < 4; ++nt) acc[nt][r] *= ar;
        }
        lsum *= alpha;
        mprev = mn;
      }
      float ps = 0.f;
      for (int st = 0; st < 4; ++st)
        for (int r = 0; r < 4; ++r) {
          float p = exp2f(sc[st][r] - mn);
          sc[st][r] = p;
          ps += p;
        }
      ps += __shfl_xor(ps, 16);
      ps += __shfl_xor(ps, 32);
      lsum += ps;
      {
        char* pw = pls[wid];
        for (int st = 0; st < 4; ++st) {
          int kk = st >> 1;
          int lqp = (st & 1) * 2 + (lq >> 1);
          uint2 pv;
          pv.x = pk2(sc[st][0], sc[st][1]);
          pv.y = pk2(sc[st][2], sc[st][3]);
          *(uint2*)(pw + kk * 1024 + (lqp * 16 + lm) * 16 + (lq & 1) * 8) = pv;
        }
      }
      asm volatile("s_waitcnt lgkmcnt(0)" ::: "memory");
      for (int kk = 0; kk < 2; ++kk) {
        f16x8 pf = *(const f16x8*)(pls[wid] + kk * 1024 + lane * 16);
        for (int nt = 0; nt < 4; ++nt) {
          f16x8 vf = *(const f16x8*)(vcur + ((nt * 2 + kk) * 64 + lane) * 16);
          acc[nt] = __builtin_amdgcn_mfma_f32_16x16x32_f16(pf, vf, acc[nt], 0, 0, 0);
        }
      }
    }
    float inv = 1.0f / lsum;
    for (int r = 0; r < 4; ++r) {
      float ir = __shfl(inv, lq * 4 + r);
      int t = qw + lq * 4 + r;
      for (int nt = 0; nt < 4; ++nt)
        ctx[((size_t)(b * T_SEQ + t) * DM) + h * DH + nt * 16 + lm] = f2h(acc[nt][r] * ir);
    }
  }
}

extern "C" void kernel_launch(void* const* d_in, const int* in_sizes, int n_in,
                              void* d_out, int out_size, void* d_ws, size_t ws_size,
                              hipStream_t stream) {
  const float* q = (const float*)d_in[0];
  const float* k = (const float*)d_in[1];
  const float* v = (const float*)d_in[2];
  const float* attn_mask = (const float*)d_in[3];
  const float* Wq = (const float*)d_in[4];
  const float* Wk = (const float*)d_in[5];
  const float* Wv = (const float*)d_in[6];
  const float* Wo = (const float*)d_in[7];
  const int* mf = (const int*)d_in[8];

  u16* ws = (u16*)d_ws;
  u16* qb  = ws;                      // f16 inputs [8192,1024] x3 (q,k,v contiguous)
  u16* wqb = ws + 3u * 8388608u;      // f16 weights x4
  u16* wkb = wqb + 1048576u;
  u16* wvb = wkb + 1048576u;
  u16* wob = wvb + 1048576u;
  u16* Qh  = wob + 1048576u;          // [bh][t][64]
  u16* Kh  = Qh + 8388608u;           // [bh][t][64]
  u16* VTh = Kh + 8388608u;           // [bh][dh][2048]
  u16* ctxb = ws;                     // alias over qb (dead after projections)

  convert_all<<<14336, 256, 0, stream>>>(q, k, v, Wq, Wk, Wv, Wo, qb, wqb);

  dim3 gq(32, 24);
  gemm_qkv<<<gq, 512, 0, stream>>>(qb, wqb, wkb, wvb, Qh, Kh, VTh);

  attn_kernel<<<512, 512, 0, stream>>>(Qh, Kh, VTh, attn_mask, mf, ctxb);

  dim3 gg(64, 8);
  gemm_out<<<gg, 256, 0, stream>>>(ctxb, wob, (float*)d_out);
}

// Round 6
// 348.504 us; speedup vs baseline: 1.0637x; 1.0316x over previous
//
#include <hip/hip_runtime.h>

typedef unsigned short u16;
typedef __attribute__((ext_vector_type(8))) _Float16 f16x8;
typedef __attribute__((ext_vector_type(2))) __fp16 fp16v2;
typedef __attribute__((ext_vector_type(4))) float f32x4;
typedef __attribute__((ext_vector_type(16))) float f32x16;

#define T_SEQ 2048
#define NH 16
#define DH 64
#define DM 1024
// NEG * log2(e), masks applied in log2 domain (softmax via exp2)
#define NEG2 (-14426.95f)
// 64^-0.25 * sqrt(log2(e)) : folded so S^T comes out pre-scaled for exp2
#define QS2 (0.42466089f)

__device__ __forceinline__ unsigned pk2(float a, float b) {
  union { fp16v2 v; unsigned u; } c;
  c.v = __builtin_amdgcn_cvt_pkrtz(a, b);
  return c.u;
}
__device__ __forceinline__ u16 f2h(float a) {
  union { _Float16 h; u16 u; } c; c.h = (_Float16)a; return c.u;
}

__device__ __forceinline__ void async_load16(const void* g, void* l) {
  __builtin_amdgcn_global_load_lds(
      (const __attribute__((address_space(1))) unsigned int*)(g),
      (__attribute__((address_space(3))) unsigned int*)(l), 16, 0, 0);
}

// ---------------- convert fp32 -> fp16 ----------------
__global__ __launch_bounds__(256) void convert_all(
    const float* __restrict__ q, const float* __restrict__ k, const float* __restrict__ v,
    const float* __restrict__ Wq, const float* __restrict__ Wk, const float* __restrict__ Wv,
    const float* __restrict__ Wo, u16* __restrict__ xb, u16* __restrict__ wb) {
  int blk = blockIdx.x;
  const float* src; u16* dst;
  if (blk < 12288) {
    int s = blk >> 12;
    src = (s == 0) ? q : (s == 1) ? k : v;
    dst = xb + (size_t)s * 8388608u;
    blk &= 4095;
  } else {
    int s = (blk - 12288) >> 9;
    src = (s == 0) ? Wq : (s == 1) ? Wk : (s == 2) ? Wv : Wo;
    dst = wb + (size_t)s * 1048576u;
    blk = (blk - 12288) & 511;
  }
  size_t base = (size_t)blk * 2048 + (size_t)threadIdx.x * 8;
  float4 a = *(const float4*)(src + base);
  float4 b2 = *(const float4*)(src + base + 4);
  uint4 st;
  st.x = pk2(a.x, a.y); st.y = pk2(a.z, a.w);
  st.z = pk2(b2.x, b2.y); st.w = pk2(b2.z, b2.w);
  *(uint4*)(dst + base) = st;
}

// ---------------- fused QKV projection GEMM: 256x128 tile, phase-split, counted vmcnt ----
// (unchanged from round 5 -- passing)
__global__ __launch_bounds__(512) void gemm_qkv(const u16* __restrict__ A,
                                                const u16* __restrict__ Wqb,
                                                const u16* __restrict__ Wkb,
                                                const u16* __restrict__ Wvb,
                                                u16* __restrict__ Qh, u16* __restrict__ Kh,
                                                u16* __restrict__ VTh) {
  __shared__ char lds[147456];  // 3 x 48KB staging; epilogue tile aliases [0, ~68KB)
  const int tid = threadIdx.x;
  const int wid = tid >> 6, lane = tid & 63;
  const int l32 = lane & 31, lh = lane >> 5;
  const int m0 = blockIdx.x * 256;               // t rows
  const int n0 = blockIdx.y * 128;               // ch cols + which
  const int which = n0 >> 10;
  const int n0l = n0 & 1023;
  const u16* As = A + (size_t)which * 8388608u;
  const u16* Bw = (which == 0) ? Wqb : (which == 1) ? Wkb : Wvb;
  f32x16 acc[2][2] = {};

  const u16* gsrc[6]; int ldso[6];
#pragma unroll
  for (int u = 0; u < 6; ++u) {
    int c = wid * 6 + u;
    ldso[u] = c * 1024;
    if (c < 32)
      gsrc[u] = As + (size_t)(m0 + (c >> 2) * 32 + l32) * 1024 + (c & 3) * 16 + lh * 8;
    else {
      int cw = c - 32;
      gsrc[u] = Bw + (size_t)(n0l + (cw >> 2) * 32 + l32) * 1024 + (cw & 3) * 16 + lh * 8;
    }
  }

  const int rOff = (which < 2) ? 32768 : 0;   // Q/K: rows = W; V: rows = X
  const int cOff = 32768 - rOff;
  const int rgo = (which < 2) ? ((wid & 1) * 2) : ((wid >> 1) * 2);
  const int cgo = (which < 2) ? ((wid >> 1) * 2) : ((wid & 1) * 2);

#pragma unroll
  for (int u = 0; u < 6; ++u) async_load16(gsrc[u] + 0 * 64, lds + 0 * 49152 + ldso[u]);
#pragma unroll
  for (int u = 0; u < 6; ++u) async_load16(gsrc[u] + 1 * 64, lds + 1 * 49152 + ldso[u]);
  asm volatile("s_waitcnt vmcnt(6)" ::: "memory");
  __builtin_amdgcn_s_barrier();
  asm volatile("" ::: "memory");

  int slotc = 0, slotn = 2;
  for (int kt = 0; kt < 16; ++kt) {
    char* bufc = lds + slotc * 49152;
    char* bufn = lds + slotn * 49152;
    const char* rb = bufc + rOff;
    const char* cb = bufc + cOff;
    f16x8 a0[4], a1[4], b0[4], b1[4];
    // ---- Phase A ----
#pragma unroll
    for (int k = 0; k < 4; ++k) {
      a0[k] = *(const f16x8*)(rb + ((rgo + 0) * 4 + k) * 1024 + lane * 16);
      b0[k] = *(const f16x8*)(cb + ((cgo + 0) * 4 + k) * 1024 + lane * 16);
      b1[k] = *(const f16x8*)(cb + ((cgo + 1) * 4 + k) * 1024 + lane * 16);
    }
    if (kt < 14) {
#pragma unroll
      for (int u = 0; u < 3; ++u) async_load16(gsrc[u] + (kt + 2) * 64, bufn + ldso[u]);
    }
    asm volatile("" ::: "memory");
    __builtin_amdgcn_s_barrier();
    asm volatile("s_waitcnt lgkmcnt(0)" ::: "memory");
    __builtin_amdgcn_sched_barrier(0);
    __builtin_amdgcn_s_setprio(1);
#pragma unroll
    for (int k = 0; k < 4; ++k) {
      acc[0][0] = __builtin_amdgcn_mfma_f32_32x32x16_f16(a0[k], b0[k], acc[0][0], 0, 0, 0);
      acc[0][1] = __builtin_amdgcn_mfma_f32_32x32x16_f16(a0[k], b1[k], acc[0][1], 0, 0, 0);
    }
    __builtin_amdgcn_s_setprio(0);
    asm volatile("" ::: "memory");
    __builtin_amdgcn_s_barrier();
    // ---- Phase B ----
#pragma unroll
    for (int k = 0; k < 4; ++k)
      a1[k] = *(const f16x8*)(rb + ((rgo + 1) * 4 + k) * 1024 + lane * 16);
    if (kt < 14) {
#pragma unroll
      for (int u = 3; u < 6; ++u) async_load16(gsrc[u] + (kt + 2) * 64, bufn + ldso[u]);
    }
    if (kt < 14) asm volatile("s_waitcnt vmcnt(6)" ::: "memory");
    else         asm volatile("s_waitcnt vmcnt(0)" ::: "memory");
    asm volatile("" ::: "memory");
    __builtin_amdgcn_s_barrier();
    asm volatile("s_waitcnt lgkmcnt(0)" ::: "memory");
    __builtin_amdgcn_sched_barrier(0);
    __builtin_amdgcn_s_setprio(1);
#pragma unroll
    for (int k = 0; k < 4; ++k) {
      acc[1][0] = __builtin_amdgcn_mfma_f32_32x32x16_f16(a1[k], b0[k], acc[1][0], 0, 0, 0);
      acc[1][1] = __builtin_amdgcn_mfma_f32_32x32x16_f16(a1[k], b1[k], acc[1][1], 0, 0, 0);
    }
    __builtin_amdgcn_s_setprio(0);
    asm volatile("" ::: "memory");
    __builtin_amdgcn_s_barrier();
    slotc = (slotc == 2) ? 0 : slotc + 1;
    slotn = (slotn == 2) ? 0 : slotn + 1;
  }

  // epilogue. C/D 32x32: col = l32, row = (reg&3)+8*(reg>>2)+4*lh.
  const float s = (which < 2) ? QS2 : 1.0f;
  const int b = m0 >> 11, t0 = m0 & 2047, h0 = n0l >> 6;
  __syncthreads();  // full drain before aliasing staging LDS
  if (which < 2) {
#pragma unroll
    for (int i = 0; i < 2; ++i)
#pragma unroll
      for (int j = 0; j < 2; ++j) {
        int colb = (wid >> 1) * 64 + j * 32 + l32;   // t_local
        int rowb = (wid & 1) * 64 + i * 32 + 4 * lh; // ch base
#pragma unroll
        for (int g = 0; g < 4; ++g) {
          uint2 pv;
          pv.x = pk2(acc[i][j][4 * g + 0] * s, acc[i][j][4 * g + 1] * s);
          pv.y = pk2(acc[i][j][4 * g + 2] * s, acc[i][j][4 * g + 3] * s);
          *(uint2*)(lds + colb * 264 + (rowb + 8 * g) * 2) = pv;
        }
      }
    __syncthreads();
    u16* O = which ? Kh : Qh;
#pragma unroll
    for (int p = 0; p < 8; ++p) {
      int row = p * 32 + (tid >> 4);  // t_local 0..255
      int seg = tid & 15;
      uint4 val = *(const uint4*)(lds + row * 264 + seg * 16);
      int hl = seg >> 3, dh0 = (seg & 7) * 8;
      *(uint4*)(O + (((size_t)(b * NH + h0 + hl) * T_SEQ + t0 + row) << 6) + dh0) = val;
    }
  } else {
#pragma unroll
    for (int i = 0; i < 2; ++i)
#pragma unroll
      for (int j = 0; j < 2; ++j) {
        int colb = (wid & 1) * 64 + j * 32 + l32;    // ch_local
        int rowb = (wid >> 1) * 64 + i * 32 + 4 * lh; // t base
#pragma unroll
        for (int g = 0; g < 4; ++g) {
          uint2 pv;
          pv.x = pk2(acc[i][j][4 * g + 0], acc[i][j][4 * g + 1]);
          pv.y = pk2(acc[i][j][4 * g + 2], acc[i][j][4 * g + 3]);
          *(uint2*)(lds + colb * 520 + (rowb + 8 * g) * 2) = pv;
        }
      }
    __syncthreads();
#pragma unroll
    for (int p = 0; p < 8; ++p) {
      int row = p * 16 + (tid >> 5);  // ch_local 0..127
      int seg = tid & 31;
      uint4 val = *(const uint4*)(lds + row * 520 + seg * 16);
      int h = h0 + (row >> 6), dh = row & 63;
      *(uint4*)(VTh + (((size_t)(b * NH + h) * DH + dh) << 11) + t0 + seg * 8) = val;
    }
  }
}

// ---------------- output projection GEMM: 256x128 tile, phase-split, counted vmcnt ----
// Same template as gemm_qkv (V path: acc rows = t, no operand swap); epilogue is
// direct fp32 global stores (no LDS transpose). Grid 32x8 = 256 blocks = 1/CU.
__global__ __launch_bounds__(512) void gemm_out(const u16* __restrict__ A,
                                                const u16* __restrict__ Bw,
                                                float* __restrict__ O) {
  __shared__ char lds[147456];
  const int tid = threadIdx.x;
  const int wid = tid >> 6, lane = tid & 63;
  const int l32 = lane & 31, lh = lane >> 5;
  const int m0 = blockIdx.x * 256, n0 = blockIdx.y * 128;
  f32x16 acc[2][2] = {};

  const u16* gsrc[6]; int ldso[6];
#pragma unroll
  for (int u = 0; u < 6; ++u) {
    int c = wid * 6 + u;
    ldso[u] = c * 1024;
    if (c < 32)
      gsrc[u] = A + (size_t)(m0 + (c >> 2) * 32 + l32) * 1024 + (c & 3) * 16 + lh * 8;
    else {
      int cw = c - 32;
      gsrc[u] = Bw + (size_t)(n0 + (cw >> 2) * 32 + l32) * 1024 + (cw & 3) * 16 + lh * 8;
    }
  }
  const int rgo = (wid >> 1) * 2, cgo = (wid & 1) * 2;

#pragma unroll
  for (int u = 0; u < 6; ++u) async_load16(gsrc[u] + 0 * 64, lds + 0 * 49152 + ldso[u]);
#pragma unroll
  for (int u = 0; u < 6; ++u) async_load16(gsrc[u] + 1 * 64, lds + 1 * 49152 + ldso[u]);
  asm volatile("s_waitcnt vmcnt(6)" ::: "memory");
  __builtin_amdgcn_s_barrier();
  asm volatile("" ::: "memory");

  int slotc = 0, slotn = 2;
  for (int kt = 0; kt < 16; ++kt) {
    char* bufc = lds + slotc * 49152;
    char* bufn = lds + slotn * 49152;
    const char* rb = bufc;           // X region (rows = t)
    const char* cb = bufc + 32768;   // W region (rows = e)
    f16x8 a0[4], a1[4], b0[4], b1[4];
    // ---- Phase A ----
#pragma unroll
    for (int k = 0; k < 4; ++k) {
      a0[k] = *(const f16x8*)(rb + ((rgo + 0) * 4 + k) * 1024 + lane * 16);
      b0[k] = *(const f16x8*)(cb + ((cgo + 0) * 4 + k) * 1024 + lane * 16);
      b1[k] = *(const f16x8*)(cb + ((cgo + 1) * 4 + k) * 1024 + lane * 16);
    }
    if (kt < 14) {
#pragma unroll
      for (int u = 0; u < 3; ++u) async_load16(gsrc[u] + (kt + 2) * 64, bufn + ldso[u]);
    }
    asm volatile("" ::: "memory");
    __builtin_amdgcn_s_barrier();
    asm volatile("s_waitcnt lgkmcnt(0)" ::: "memory");
    __builtin_amdgcn_sched_barrier(0);
    __builtin_amdgcn_s_setprio(1);
#pragma unroll
    for (int k = 0; k < 4; ++k) {
      acc[0][0] = __builtin_amdgcn_mfma_f32_32x32x16_f16(a0[k], b0[k], acc[0][0], 0, 0, 0);
      acc[0][1] = __builtin_amdgcn_mfma_f32_32x32x16_f16(a0[k], b1[k], acc[0][1], 0, 0, 0);
    }
    __builtin_amdgcn_s_setprio(0);
    asm volatile("" ::: "memory");
    __builtin_amdgcn_s_barrier();
    // ---- Phase B ----
#pragma unroll
    for (int k = 0; k < 4; ++k)
      a1[k] = *(const f16x8*)(rb + ((rgo + 1) * 4 + k) * 1024 + lane * 16);
    if (kt < 14) {
#pragma unroll
      for (int u = 3; u < 6; ++u) async_load16(gsrc[u] + (kt + 2) * 64, bufn + ldso[u]);
    }
    if (kt < 14) asm volatile("s_waitcnt vmcnt(6)" ::: "memory");
    else         asm volatile("s_waitcnt vmcnt(0)" ::: "memory");
    asm volatile("" ::: "memory");
    __builtin_amdgcn_s_barrier();
    asm volatile("s_waitcnt lgkmcnt(0)" ::: "memory");
    __builtin_amdgcn_sched_barrier(0);
    __builtin_amdgcn_s_setprio(1);
#pragma unroll
    for (int k = 0; k < 4; ++k) {
      acc[1][0] = __builtin_amdgcn_mfma_f32_32x32x16_f16(a1[k], b0[k], acc[1][0], 0, 0, 0);
      acc[1][1] = __builtin_amdgcn_mfma_f32_32x32x16_f16(a1[k], b1[k], acc[1][1], 0, 0, 0);
    }
    __builtin_amdgcn_s_setprio(0);
    asm volatile("" ::: "memory");
    __builtin_amdgcn_s_barrier();
    slotc = (slotc == 2) ? 0 : slotc + 1;
    slotn = (slotn == 2) ? 0 : slotn + 1;
  }
  // epilogue: direct fp32 stores. row = rowb + 8*g + rr, col contiguous over l32.
#pragma unroll
  for (int i = 0; i < 2; ++i)
#pragma unroll
    for (int j = 0; j < 2; ++j) {
      int col = n0 + (wid & 1) * 64 + j * 32 + l32;
      int rowb = m0 + (wid >> 1) * 64 + i * 32 + 4 * lh;
#pragma unroll
      for (int g = 0; g < 4; ++g)
#pragma unroll
        for (int rr = 0; rr < 4; ++rr)
          O[(size_t)(rowb + 8 * g + rr) * 1024 + col] = acc[i][j][4 * g + rr];
    }
}

// ---------------- Flash attention (S^T formulation, fp16, 8 waves) ----------------
// Round-6 changes (VALU-trim; staging/barrier structure unchanged from passing r5):
//  - defer-max (THR=8 in log2 domain): skip the O/lsum rescale unless the chunk max
//    exceeds the running max by >8; P is then bounded by 2^8=256 (safe in f16),
//    lsum/acc stay consistent since both use the same running max.
//  - max3-shaped 16-element max reduction (8 ops, fmaxf triples fuse to v_max3).
__global__ __launch_bounds__(512) void attn_kernel(const u16* __restrict__ Qh,
                                                   const u16* __restrict__ Kh,
                                                   const u16* __restrict__ VTh,
                                                   const float* __restrict__ attn_mask,
                                                   const int* __restrict__ mfp,
                                                   u16* __restrict__ ctx) {
  __shared__ char kls[2][8192];   // K chunk (64s x 64k), cells (st*2+kk), x2 dbuf
  __shared__ char vls[2][8192];   // V^T chunk (64dh x 64s), cells (nt*2+kk), x2 dbuf
  __shared__ char pls[8][2048];   // per-wave P (16q x 64s) in A-frag order
  __shared__ float maskb[T_SEQ];  // pad bias in log2 domain
  __shared__ int mzf;             // 1 if any pad-mask zero for this b

  const int tid = threadIdx.x;
  const int wid = tid >> 6, lane = tid & 63;
  const int lm = lane & 15, lq = lane >> 4;
  const int bid = blockIdx.x;
  const int bh_i = bid & 63, p8 = bid >> 6;
  const int b = bh_i >> 4, h = bh_i & 15;
  const int mf = *mfp;
  const size_t bh = (size_t)(b * NH + h);
  const u16* Qbh = Qh + bh * T_SEQ * DH;
  const u16* Kbh = Kh + bh * T_SEQ * DH;
  const u16* VTbh = VTh + bh * DH * T_SEQ;

  if (tid == 0) mzf = 0;
  __syncthreads();
  {
    int az = 0;
    for (int i = tid; i < T_SEQ; i += 512) {
      float mv = attn_mask[(size_t)b * T_SEQ + i];
      maskb[i] = (mv == 0.0f) ? NEG2 : 0.0f;
      az |= (mv == 0.0f);
    }
    if (az) mzf = 1;  // benign same-value race
  }
  __syncthreads();
  const int maskzero = mzf;

  for (int half = 0; half < 2; ++half) {
    const int qt = half ? (15 - p8) : p8;   // 128-row q-tile index
    const int q0 = qt * 128;
    const int qw = q0 + wid * 16;
    f16x8 qf[2];
    qf[0] = *(const f16x8*)(Qbh + (size_t)(qw + lm) * DH + lq * 8);
    qf[1] = *(const f16x8*)(Qbh + (size_t)(qw + lm) * DH + 32 + lq * 8);

    f32x4 acc[4] = {};
    float mprev = -1e30f, lsum = 0.f;

    const int nch = mf ? (qt + 1) * 2 : 32;
    __syncthreads();
    {
      async_load16(Kbh + (size_t)((wid >> 1) * 16 + lm) * DH + (wid & 1) * 32 + lq * 8,
                   kls[0] + wid * 1024);
      async_load16(VTbh + (size_t)((wid >> 1) * 16 + lm) * T_SEQ + (wid & 1) * 32 + lq * 8,
                   vls[0] + wid * 1024);
    }
    for (int c = 0; c < nch; ++c) {
      const int s0 = c * 64;
      asm volatile("s_waitcnt vmcnt(0)" ::: "memory");
      __builtin_amdgcn_s_barrier();
      asm volatile("" ::: "memory");
      if (c + 1 < nch) {
        const int s1 = s0 + 64;
        async_load16(Kbh + (size_t)(s1 + (wid >> 1) * 16 + lm) * DH + (wid & 1) * 32 + lq * 8,
                     kls[(c + 1) & 1] + wid * 1024);
        async_load16(VTbh + (size_t)((wid >> 1) * 16 + lm) * T_SEQ + s1 + (wid & 1) * 32 + lq * 8,
                     vls[(c + 1) & 1] + wid * 1024);
      }
      const char* kcur = kls[c & 1];
      const char* vcur = vls[c & 1];

      f32x4 sc[4];
      for (int st = 0; st < 4; ++st) {
        f32x4 z = {0.f, 0.f, 0.f, 0.f};
        sc[st] = z;
        for (int kk = 0; kk < 2; ++kk) {
          f16x8 kf = *(const f16x8*)(kcur + ((st * 2 + kk) * 64 + lane) * 16);
          sc[st] = __builtin_amdgcn_mfma_f32_16x16x32_f16(kf, qf[kk], sc[st], 0, 0, 0);
        }
      }
      if (maskzero) {
        for (int st = 0; st < 4; ++st) {
          f32x4 mb = *(const f32x4*)(maskb + s0 + st * 16 + lq * 4);
          for (int r = 0; r < 4; ++r) sc[st][r] += mb[r];
        }
      }
      if (mf && (s0 + 64 > qw)) {
        int qg = qw + lm;
        for (int st = 0; st < 4; ++st)
          for (int r = 0; r < 4; ++r)
            if (s0 + st * 16 + lq * 4 + r > qg) sc[st][r] = NEG2;
      }
      // chunk max via max3-shaped tree (8 ops)
      float u0 = fmaxf(fmaxf(sc[0][0], sc[0][1]), sc[0][2]);
      float u1 = fmaxf(fmaxf(sc[0][3], sc[1][0]), sc[1][1]);
      float u2 = fmaxf(fmaxf(sc[1][2], sc[1][3]), sc[2][0]);
      float u3 = fmaxf(fmaxf(sc[2][1], sc[2][2]), sc[2][3]);
      float u4 = fmaxf(fmaxf(sc[3][0], sc[3][1]), sc[3][2]);
      float mx = fmaxf(fmaxf(fmaxf(u0, u1), u2), fmaxf(fmaxf(u3, u4), sc[3][3]));
      mx = fmaxf(mx, __shfl_xor(mx, 16));
      mx = fmaxf(mx, __shfl_xor(mx, 32));
      // defer-max: rescale only when the max grew by more than THR=8 (log2 domain).
      // Otherwise keep mprev; P <= 2^8 = 256, safe in f16.
      if (__ballot(mx > mprev + 8.0f) != 0ull) {
        float mn2 = fmaxf(mprev, mx);
        float alpha = exp2f(mprev - mn2);
        for (int r = 0; r < 4; ++r) {
          float ar = __shfl(alpha, lq * 4 + r);
          for (int nt = 0; nt < 4; ++nt) acc[nt][r] *= ar;
        }
        lsum *= alpha;
        mprev = mn2;
      }
      float ps = 0.f;
      for (int st = 0; st < 4; ++st)
        for (int r = 0; r < 4; ++r) {
          float p = exp2f(sc[st][r] - mprev);
          sc[st][r] = p;
          ps += p;
        }
      ps += __shfl_xor(ps, 16);
      ps += __shfl_xor(ps, 32);
      lsum += ps;
      {
        char* pw = pls[wid];
        for (int st = 0; st < 4; ++st) {
          int kk = st >> 1;
          int lqp = (st & 1) * 2 + (lq >> 1);
          uint2 pv;
          pv.x = pk2(sc[st][0], sc[st][1]);
          pv.y = pk2(sc[st][2], sc[st][3]);
          *(uint2*)(pw + kk * 1024 + (lqp * 16 + lm) * 16 + (lq & 1) * 8) = pv;
        }
      }
      asm volatile("s_waitcnt lgkmcnt(0)" ::: "memory");
      for (int kk = 0; kk < 2; ++kk) {
        f16x8 pf = *(const f16x8*)(pls[wid] + kk * 1024 + lane * 16);
        for (int nt = 0; nt < 4; ++nt) {
          f16x8 vf = *(const f16x8*)(vcur + ((nt * 2 + kk) * 64 + lane) * 16);
          acc[nt] = __builtin_amdgcn_mfma_f32_16x16x32_f16(pf, vf, acc[nt], 0, 0, 0);
        }
      }
    }
    float inv = 1.0f / lsum;
    for (int r = 0; r < 4; ++r) {
      float ir = __shfl(inv, lq * 4 + r);
      int t = qw + lq * 4 + r;
      for (int nt = 0; nt < 4; ++nt)
        ctx[((size_t)(b * T_SEQ + t) * DM) + h * DH + nt * 16 + lm] = f2h(acc[nt][r] * ir);
    }
  }
}

extern "C" void kernel_launch(void* const* d_in, const int* in_sizes, int n_in,
                              void* d_out, int out_size, void* d_ws, size_t ws_size,
                              hipStream_t stream) {
  const float* q = (const float*)d_in[0];
  const float* k = (const float*)d_in[1];
  const float* v = (const float*)d_in[2];
  const float* attn_mask = (const float*)d_in[3];
  const float* Wq = (const float*)d_in[4];
  const float* Wk = (const float*)d_in[5];
  const float* Wv = (const float*)d_in[6];
  const float* Wo = (const float*)d_in[7];
  const int* mf = (const int*)d_in[8];

  u16* ws = (u16*)d_ws;
  u16* qb  = ws;                      // f16 inputs [8192,1024] x3 (q,k,v contiguous)
  u16* wqb = ws + 3u * 8388608u;      // f16 weights x4
  u16* wkb = wqb + 1048576u;
  u16* wvb = wkb + 1048576u;
  u16* wob = wvb + 1048576u;
  u16* Qh  = wob + 1048576u;          // [bh][t][64]
  u16* Kh  = Qh + 8388608u;           // [bh][t][64]
  u16* VTh = Kh + 8388608u;           // [bh][dh][2048]
  u16* ctxb = ws;                     // alias over qb (dead after projections)

  convert_all<<<14336, 256, 0, stream>>>(q, k, v, Wq, Wk, Wv, Wo, qb, wqb);

  dim3 gq(32, 24);
  gemm_qkv<<<gq, 512, 0, stream>>>(qb, wqb, wkb, wvb, Qh, Kh, VTh);

  attn_kernel<<<512, 512, 0, stream>>>(Qh, Kh, VTh, attn_mask, mf, ctxb);

  dim3 gg(32, 8);
  gemm_out<<<gg, 512, 0, stream>>>(ctxb, wob, (float*)d_out);
}

// Round 7
// 346.869 us; speedup vs baseline: 1.0687x; 1.0047x over previous
//
#include <hip/hip_runtime.h>

typedef unsigned short u16;
typedef __attribute__((ext_vector_type(8))) _Float16 f16x8;
typedef __attribute__((ext_vector_type(2))) __fp16 fp16v2;
typedef __attribute__((ext_vector_type(4))) float f32x4;
typedef __attribute__((ext_vector_type(16))) float f32x16;

#define T_SEQ 2048
#define NH 16
#define DH 64
#define DM 1024
// NEG * log2(e), masks applied in log2 domain (softmax via exp2)
#define NEG2 (-14426.95f)
// 64^-0.25 * sqrt(log2(e)) : folded so S^T comes out pre-scaled for exp2
#define QS2 (0.42466089f)

__device__ __forceinline__ unsigned pk2(float a, float b) {
  union { fp16v2 v; unsigned u; } c;
  c.v = __builtin_amdgcn_cvt_pkrtz(a, b);
  return c.u;
}
__device__ __forceinline__ u16 f2h(float a) {
  union { _Float16 h; u16 u; } c; c.h = (_Float16)a; return c.u;
}

__device__ __forceinline__ void async_load16(const void* g, void* l) {
  __builtin_amdgcn_global_load_lds(
      (const __attribute__((address_space(1))) unsigned int*)(g),
      (__attribute__((address_space(3))) unsigned int*)(l), 16, 0, 0);
}

// ---------------- convert fp32 -> fp16 ----------------
__global__ __launch_bounds__(256) void convert_all(
    const float* __restrict__ q, const float* __restrict__ k, const float* __restrict__ v,
    const float* __restrict__ Wq, const float* __restrict__ Wk, const float* __restrict__ Wv,
    const float* __restrict__ Wo, u16* __restrict__ xb, u16* __restrict__ wb) {
  int blk = blockIdx.x;
  const float* src; u16* dst;
  if (blk < 12288) {
    int s = blk >> 12;
    src = (s == 0) ? q : (s == 1) ? k : v;
    dst = xb + (size_t)s * 8388608u;
    blk &= 4095;
  } else {
    int s = (blk - 12288) >> 9;
    src = (s == 0) ? Wq : (s == 1) ? Wk : (s == 2) ? Wv : Wo;
    dst = wb + (size_t)s * 1048576u;
    blk = (blk - 12288) & 511;
  }
  size_t base = (size_t)blk * 2048 + (size_t)threadIdx.x * 8;
  float4 a = *(const float4*)(src + base);
  float4 b2 = *(const float4*)(src + base + 4);
  uint4 st;
  st.x = pk2(a.x, a.y); st.y = pk2(a.z, a.w);
  st.z = pk2(b2.x, b2.y); st.w = pk2(b2.z, b2.w);
  *(uint4*)(dst + base) = st;
}

// ---------------- fused QKV projection GEMM: 256x128 tile, phase-split, counted vmcnt ----
// (unchanged -- passing)
__global__ __launch_bounds__(512) void gemm_qkv(const u16* __restrict__ A,
                                                const u16* __restrict__ Wqb,
                                                const u16* __restrict__ Wkb,
                                                const u16* __restrict__ Wvb,
                                                u16* __restrict__ Qh, u16* __restrict__ Kh,
                                                u16* __restrict__ VTh) {
  __shared__ char lds[147456];  // 3 x 48KB staging; epilogue tile aliases [0, ~68KB)
  const int tid = threadIdx.x;
  const int wid = tid >> 6, lane = tid & 63;
  const int l32 = lane & 31, lh = lane >> 5;
  const int m0 = blockIdx.x * 256;               // t rows
  const int n0 = blockIdx.y * 128;               // ch cols + which
  const int which = n0 >> 10;
  const int n0l = n0 & 1023;
  const u16* As = A + (size_t)which * 8388608u;
  const u16* Bw = (which == 0) ? Wqb : (which == 1) ? Wkb : Wvb;
  f32x16 acc[2][2] = {};

  const u16* gsrc[6]; int ldso[6];
#pragma unroll
  for (int u = 0; u < 6; ++u) {
    int c = wid * 6 + u;
    ldso[u] = c * 1024;
    if (c < 32)
      gsrc[u] = As + (size_t)(m0 + (c >> 2) * 32 + l32) * 1024 + (c & 3) * 16 + lh * 8;
    else {
      int cw = c - 32;
      gsrc[u] = Bw + (size_t)(n0l + (cw >> 2) * 32 + l32) * 1024 + (cw & 3) * 16 + lh * 8;
    }
  }

  const int rOff = (which < 2) ? 32768 : 0;   // Q/K: rows = W; V: rows = X
  const int cOff = 32768 - rOff;
  const int rgo = (which < 2) ? ((wid & 1) * 2) : ((wid >> 1) * 2);
  const int cgo = (which < 2) ? ((wid >> 1) * 2) : ((wid & 1) * 2);

#pragma unroll
  for (int u = 0; u < 6; ++u) async_load16(gsrc[u] + 0 * 64, lds + 0 * 49152 + ldso[u]);
#pragma unroll
  for (int u = 0; u < 6; ++u) async_load16(gsrc[u] + 1 * 64, lds + 1 * 49152 + ldso[u]);
  asm volatile("s_waitcnt vmcnt(6)" ::: "memory");
  __builtin_amdgcn_s_barrier();
  asm volatile("" ::: "memory");

  int slotc = 0, slotn = 2;
  for (int kt = 0; kt < 16; ++kt) {
    char* bufc = lds + slotc * 49152;
    char* bufn = lds + slotn * 49152;
    const char* rb = bufc + rOff;
    const char* cb = bufc + cOff;
    f16x8 a0[4], a1[4], b0[4], b1[4];
    // ---- Phase A ----
#pragma unroll
    for (int k = 0; k < 4; ++k) {
      a0[k] = *(const f16x8*)(rb + ((rgo + 0) * 4 + k) * 1024 + lane * 16);
      b0[k] = *(const f16x8*)(cb + ((cgo + 0) * 4 + k) * 1024 + lane * 16);
      b1[k] = *(const f16x8*)(cb + ((cgo + 1) * 4 + k) * 1024 + lane * 16);
    }
    if (kt < 14) {
#pragma unroll
      for (int u = 0; u < 3; ++u) async_load16(gsrc[u] + (kt + 2) * 64, bufn + ldso[u]);
    }
    asm volatile("" ::: "memory");
    __builtin_amdgcn_s_barrier();
    asm volatile("s_waitcnt lgkmcnt(0)" ::: "memory");
    __builtin_amdgcn_sched_barrier(0);
    __builtin_amdgcn_s_setprio(1);
#pragma unroll
    for (int k = 0; k < 4; ++k) {
      acc[0][0] = __builtin_amdgcn_mfma_f32_32x32x16_f16(a0[k], b0[k], acc[0][0], 0, 0, 0);
      acc[0][1] = __builtin_amdgcn_mfma_f32_32x32x16_f16(a0[k], b1[k], acc[0][1], 0, 0, 0);
    }
    __builtin_amdgcn_s_setprio(0);
    asm volatile("" ::: "memory");
    __builtin_amdgcn_s_barrier();
    // ---- Phase B ----
#pragma unroll
    for (int k = 0; k < 4; ++k)
      a1[k] = *(const f16x8*)(rb + ((rgo + 1) * 4 + k) * 1024 + lane * 16);
    if (kt < 14) {
#pragma unroll
      for (int u = 3; u < 6; ++u) async_load16(gsrc[u] + (kt + 2) * 64, bufn + ldso[u]);
    }
    if (kt < 14) asm volatile("s_waitcnt vmcnt(6)" ::: "memory");
    else         asm volatile("s_waitcnt vmcnt(0)" ::: "memory");
    asm volatile("" ::: "memory");
    __builtin_amdgcn_s_barrier();
    asm volatile("s_waitcnt lgkmcnt(0)" ::: "memory");
    __builtin_amdgcn_sched_barrier(0);
    __builtin_amdgcn_s_setprio(1);
#pragma unroll
    for (int k = 0; k < 4; ++k) {
      acc[1][0] = __builtin_amdgcn_mfma_f32_32x32x16_f16(a1[k], b0[k], acc[1][0], 0, 0, 0);
      acc[1][1] = __builtin_amdgcn_mfma_f32_32x32x16_f16(a1[k], b1[k], acc[1][1], 0, 0, 0);
    }
    __builtin_amdgcn_s_setprio(0);
    asm volatile("" ::: "memory");
    __builtin_amdgcn_s_barrier();
    slotc = (slotc == 2) ? 0 : slotc + 1;
    slotn = (slotn == 2) ? 0 : slotn + 1;
  }

  // epilogue. C/D 32x32: col = l32, row = (reg&3)+8*(reg>>2)+4*lh.
  const float s = (which < 2) ? QS2 : 1.0f;
  const int b = m0 >> 11, t0 = m0 & 2047, h0 = n0l >> 6;
  __syncthreads();  // full drain before aliasing staging LDS
  if (which < 2) {
#pragma unroll
    for (int i = 0; i < 2; ++i)
#pragma unroll
      for (int j = 0; j < 2; ++j) {
        int colb = (wid >> 1) * 64 + j * 32 + l32;   // t_local
        int rowb = (wid & 1) * 64 + i * 32 + 4 * lh; // ch base
#pragma unroll
        for (int g = 0; g < 4; ++g) {
          uint2 pv;
          pv.x = pk2(acc[i][j][4 * g + 0] * s, acc[i][j][4 * g + 1] * s);
          pv.y = pk2(acc[i][j][4 * g + 2] * s, acc[i][j][4 * g + 3] * s);
          *(uint2*)(lds + colb * 264 + (rowb + 8 * g) * 2) = pv;
        }
      }
    __syncthreads();
    u16* O = which ? Kh : Qh;
#pragma unroll
    for (int p = 0; p < 8; ++p) {
      int row = p * 32 + (tid >> 4);  // t_local 0..255
      int seg = tid & 15;
      uint4 val = *(const uint4*)(lds + row * 264 + seg * 16);
      int hl = seg >> 3, dh0 = (seg & 7) * 8;
      *(uint4*)(O + (((size_t)(b * NH + h0 + hl) * T_SEQ + t0 + row) << 6) + dh0) = val;
    }
  } else {
#pragma unroll
    for (int i = 0; i < 2; ++i)
#pragma unroll
      for (int j = 0; j < 2; ++j) {
        int colb = (wid & 1) * 64 + j * 32 + l32;    // ch_local
        int rowb = (wid >> 1) * 64 + i * 32 + 4 * lh; // t base
#pragma unroll
        for (int g = 0; g < 4; ++g) {
          uint2 pv;
          pv.x = pk2(acc[i][j][4 * g + 0], acc[i][j][4 * g + 1]);
          pv.y = pk2(acc[i][j][4 * g + 2], acc[i][j][4 * g + 3]);
          *(uint2*)(lds + colb * 520 + (rowb + 8 * g) * 2) = pv;
        }
      }
    __syncthreads();
#pragma unroll
    for (int p = 0; p < 8; ++p) {
      int row = p * 16 + (tid >> 5);  // ch_local 0..127
      int seg = tid & 31;
      uint4 val = *(const uint4*)(lds + row * 520 + seg * 16);
      int h = h0 + (row >> 6), dh = row & 63;
      *(uint4*)(VTh + (((size_t)(b * NH + h) * DH + dh) << 11) + t0 + seg * 8) = val;
    }
  }
}

// ---------------- output projection GEMM: 256x128 tile, phase-split, counted vmcnt ----
// (unchanged -- passing)
__global__ __launch_bounds__(512) void gemm_out(const u16* __restrict__ A,
                                                const u16* __restrict__ Bw,
                                                float* __restrict__ O) {
  __shared__ char lds[147456];
  const int tid = threadIdx.x;
  const int wid = tid >> 6, lane = tid & 63;
  const int l32 = lane & 31, lh = lane >> 5;
  const int m0 = blockIdx.x * 256, n0 = blockIdx.y * 128;
  f32x16 acc[2][2] = {};

  const u16* gsrc[6]; int ldso[6];
#pragma unroll
  for (int u = 0; u < 6; ++u) {
    int c = wid * 6 + u;
    ldso[u] = c * 1024;
    if (c < 32)
      gsrc[u] = A + (size_t)(m0 + (c >> 2) * 32 + l32) * 1024 + (c & 3) * 16 + lh * 8;
    else {
      int cw = c - 32;
      gsrc[u] = Bw + (size_t)(n0 + (cw >> 2) * 32 + l32) * 1024 + (cw & 3) * 16 + lh * 8;
    }
  }
  const int rgo = (wid >> 1) * 2, cgo = (wid & 1) * 2;

#pragma unroll
  for (int u = 0; u < 6; ++u) async_load16(gsrc[u] + 0 * 64, lds + 0 * 49152 + ldso[u]);
#pragma unroll
  for (int u = 0; u < 6; ++u) async_load16(gsrc[u] + 1 * 64, lds + 1 * 49152 + ldso[u]);
  asm volatile("s_waitcnt vmcnt(6)" ::: "memory");
  __builtin_amdgcn_s_barrier();
  asm volatile("" ::: "memory");

  int slotc = 0, slotn = 2;
  for (int kt = 0; kt < 16; ++kt) {
    char* bufc = lds + slotc * 49152;
    char* bufn = lds + slotn * 49152;
    const char* rb = bufc;           // X region (rows = t)
    const char* cb = bufc + 32768;   // W region (rows = e)
    f16x8 a0[4], a1[4], b0[4], b1[4];
    // ---- Phase A ----
#pragma unroll
    for (int k = 0; k < 4; ++k) {
      a0[k] = *(const f16x8*)(rb + ((rgo + 0) * 4 + k) * 1024 + lane * 16);
      b0[k] = *(const f16x8*)(cb + ((cgo + 0) * 4 + k) * 1024 + lane * 16);
      b1[k] = *(const f16x8*)(cb + ((cgo + 1) * 4 + k) * 1024 + lane * 16);
    }
    if (kt < 14) {
#pragma unroll
      for (int u = 0; u < 3; ++u) async_load16(gsrc[u] + (kt + 2) * 64, bufn + ldso[u]);
    }
    asm volatile("" ::: "memory");
    __builtin_amdgcn_s_barrier();
    asm volatile("s_waitcnt lgkmcnt(0)" ::: "memory");
    __builtin_amdgcn_sched_barrier(0);
    __builtin_amdgcn_s_setprio(1);
#pragma unroll
    for (int k = 0; k < 4; ++k) {
      acc[0][0] = __builtin_amdgcn_mfma_f32_32x32x16_f16(a0[k], b0[k], acc[0][0], 0, 0, 0);
      acc[0][1] = __builtin_amdgcn_mfma_f32_32x32x16_f16(a0[k], b1[k], acc[0][1], 0, 0, 0);
    }
    __builtin_amdgcn_s_setprio(0);
    asm volatile("" ::: "memory");
    __builtin_amdgcn_s_barrier();
    // ---- Phase B ----
#pragma unroll
    for (int k = 0; k < 4; ++k)
      a1[k] = *(const f16x8*)(rb + ((rgo + 1) * 4 + k) * 1024 + lane * 16);
    if (kt < 14) {
#pragma unroll
      for (int u = 3; u < 6; ++u) async_load16(gsrc[u] + (kt + 2) * 64, bufn + ldso[u]);
    }
    if (kt < 14) asm volatile("s_waitcnt vmcnt(6)" ::: "memory");
    else         asm volatile("s_waitcnt vmcnt(0)" ::: "memory");
    asm volatile("" ::: "memory");
    __builtin_amdgcn_s_barrier();
    asm volatile("s_waitcnt lgkmcnt(0)" ::: "memory");
    __builtin_amdgcn_sched_barrier(0);
    __builtin_amdgcn_s_setprio(1);
#pragma unroll
    for (int k = 0; k < 4; ++k) {
      acc[1][0] = __builtin_amdgcn_mfma_f32_32x32x16_f16(a1[k], b0[k], acc[1][0], 0, 0, 0);
      acc[1][1] = __builtin_amdgcn_mfma_f32_32x32x16_f16(a1[k], b1[k], acc[1][1], 0, 0, 0);
    }
    __builtin_amdgcn_s_setprio(0);
    asm volatile("" ::: "memory");
    __builtin_amdgcn_s_barrier();
    slotc = (slotc == 2) ? 0 : slotc + 1;
    slotn = (slotn == 2) ? 0 : slotn + 1;
  }
  // epilogue: direct fp32 stores. row = rowb + 8*g + rr, col contiguous over l32.
#pragma unroll
  for (int i = 0; i < 2; ++i)
#pragma unroll
    for (int j = 0; j < 2; ++j) {
      int col = n0 + (wid & 1) * 64 + j * 32 + l32;
      int rowb = m0 + (wid >> 1) * 64 + i * 32 + 4 * lh;
#pragma unroll
      for (int g = 0; g < 4; ++g)
#pragma unroll
        for (int rr = 0; rr < 4; ++rr)
          O[(size_t)(rowb + 8 * g + rr) * 1024 + col] = acc[i][j][4 * g + rr];
    }
}

// ---------------- Flash attention (S^T formulation, fp16, 8 waves) ----------------
// Round-7 changes (occupancy + MFMA-offload; staging/barriers unchanged):
//  - maskb LDS array REMOVED (8KB): pad bias now read straight from global
//    attn_mask only when the mask actually has zeros (maskzero path). LDS
//    drops to ~49.2KB -> 3 blocks/CU (was 2).
//  - row-sum via MFMA: accs = mfma(pf, ones, accs) accumulates sum_s P[q][s]
//    in an extra accumulator that rescales with acc (same ar), replacing the
//    16-add ps chain + 2 shfl + scalar lsum; accs[r] is row-indexed so the
//    epilogue's shfl(inv) disappears too.
__global__ __launch_bounds__(512) void attn_kernel(const u16* __restrict__ Qh,
                                                   const u16* __restrict__ Kh,
                                                   const u16* __restrict__ VTh,
                                                   const float* __restrict__ attn_mask,
                                                   const int* __restrict__ mfp,
                                                   u16* __restrict__ ctx) {
  __shared__ char kls[2][8192];   // K chunk (64s x 64k), cells (st*2+kk), x2 dbuf
  __shared__ char vls[2][8192];   // V^T chunk (64dh x 64s), cells (nt*2+kk), x2 dbuf
  __shared__ char pls[8][2048];   // per-wave P (16q x 64s) in A-frag order
  __shared__ int mzf;             // 1 if any pad-mask zero for this b

  const int tid = threadIdx.x;
  const int wid = tid >> 6, lane = tid & 63;
  const int lm = lane & 15, lq = lane >> 4;
  const int bid = blockIdx.x;
  const int bh_i = bid & 63, p8 = bid >> 6;
  const int b = bh_i >> 4, h = bh_i & 15;
  const int mf = *mfp;
  const size_t bh = (size_t)(b * NH + h);
  const u16* Qbh = Qh + bh * T_SEQ * DH;
  const u16* Kbh = Kh + bh * T_SEQ * DH;
  const u16* VTbh = VTh + bh * DH * T_SEQ;
  const float* amb = attn_mask + (size_t)b * T_SEQ;

  f16x8 onev;
#pragma unroll
  for (int i = 0; i < 8; ++i) onev[i] = (_Float16)1.0f;

  if (tid == 0) mzf = 0;
  __syncthreads();
  {
    int az = 0;
    for (int i = tid; i < T_SEQ; i += 512) az |= (amb[i] == 0.0f);
    if (az) mzf = 1;  // benign same-value race
  }
  __syncthreads();
  const int maskzero = mzf;

  for (int half = 0; half < 2; ++half) {
    const int qt = half ? (15 - p8) : p8;   // 128-row q-tile index
    const int q0 = qt * 128;
    const int qw = q0 + wid * 16;
    f16x8 qf[2];
    qf[0] = *(const f16x8*)(Qbh + (size_t)(qw + lm) * DH + lq * 8);
    qf[1] = *(const f16x8*)(Qbh + (size_t)(qw + lm) * DH + 32 + lq * 8);

    f32x4 acc[4] = {};
    f32x4 accs = {};                 // row-sum accumulator: accs[r] = lsum(q=lq*4+r)
    float mprev = -1e30f;

    const int nch = mf ? (qt + 1) * 2 : 32;
    __syncthreads();
    {
      async_load16(Kbh + (size_t)((wid >> 1) * 16 + lm) * DH + (wid & 1) * 32 + lq * 8,
                   kls[0] + wid * 1024);
      async_load16(VTbh + (size_t)((wid >> 1) * 16 + lm) * T_SEQ + (wid & 1) * 32 + lq * 8,
                   vls[0] + wid * 1024);
    }
    for (int c = 0; c < nch; ++c) {
      const int s0 = c * 64;
      asm volatile("s_waitcnt vmcnt(0)" ::: "memory");
      __builtin_amdgcn_s_barrier();
      asm volatile("" ::: "memory");
      if (c + 1 < nch) {
        const int s1 = s0 + 64;
        async_load16(Kbh + (size_t)(s1 + (wid >> 1) * 16 + lm) * DH + (wid & 1) * 32 + lq * 8,
                     kls[(c + 1) & 1] + wid * 1024);
        async_load16(VTbh + (size_t)((wid >> 1) * 16 + lm) * T_SEQ + s1 + (wid & 1) * 32 + lq * 8,
                     vls[(c + 1) & 1] + wid * 1024);
      }
      const char* kcur = kls[c & 1];
      const char* vcur = vls[c & 1];

      f32x4 sc[4];
      for (int st = 0; st < 4; ++st) {
        f32x4 z = {0.f, 0.f, 0.f, 0.f};
        sc[st] = z;
        for (int kk = 0; kk < 2; ++kk) {
          f16x8 kf = *(const f16x8*)(kcur + ((st * 2 + kk) * 64 + lane) * 16);
          sc[st] = __builtin_amdgcn_mfma_f32_16x16x32_f16(kf, qf[kk], sc[st], 0, 0, 0);
        }
      }
      if (maskzero) {  // rare path: pad bias straight from global (L2-resident)
        for (int st = 0; st < 4; ++st) {
          f32x4 mb = *(const f32x4*)(amb + s0 + st * 16 + lq * 4);
          for (int r = 0; r < 4; ++r)
            if (mb[r] == 0.0f) sc[st][r] += NEG2;
        }
      }
      if (mf && (s0 + 64 > qw)) {
        int qg = qw + lm;
        for (int st = 0; st < 4; ++st)
          for (int r = 0; r < 4; ++r)
            if (s0 + st * 16 + lq * 4 + r > qg) sc[st][r] = NEG2;
      }
      // chunk max via max3-shaped tree (8 ops)
      float u0 = fmaxf(fmaxf(sc[0][0], sc[0][1]), sc[0][2]);
      float u1 = fmaxf(fmaxf(sc[0][3], sc[1][0]), sc[1][1]);
      float u2 = fmaxf(fmaxf(sc[1][2], sc[1][3]), sc[2][0]);
      float u3 = fmaxf(fmaxf(sc[2][1], sc[2][2]), sc[2][3]);
      float u4 = fmaxf(fmaxf(sc[3][0], sc[3][1]), sc[3][2]);
      float mx = fmaxf(fmaxf(fmaxf(u0, u1), u2), fmaxf(fmaxf(u3, u4), sc[3][3]));
      mx = fmaxf(mx, __shfl_xor(mx, 16));
      mx = fmaxf(mx, __shfl_xor(mx, 32));
      // defer-max: rescale only when the max grew by more than THR=8 (log2 domain)
      if (__ballot(mx > mprev + 8.0f) != 0ull) {
        float mn2 = fmaxf(mprev, mx);
        float alpha = exp2f(mprev - mn2);
        for (int r = 0; r < 4; ++r) {
          float ar = __shfl(alpha, lq * 4 + r);
          for (int nt = 0; nt < 4; ++nt) acc[nt][r] *= ar;
          accs[r] *= ar;
        }
        mprev = mn2;
      }
      for (int st = 0; st < 4; ++st)
        for (int r = 0; r < 4; ++r)
          sc[st][r] = exp2f(sc[st][r] - mprev);
      {
        char* pw = pls[wid];
        for (int st = 0; st < 4; ++st) {
          int kk = st >> 1;
          int lqp = (st & 1) * 2 + (lq >> 1);
          uint2 pv;
          pv.x = pk2(sc[st][0], sc[st][1]);
          pv.y = pk2(sc[st][2], sc[st][3]);
          *(uint2*)(pw + kk * 1024 + (lqp * 16 + lm) * 16 + (lq & 1) * 8) = pv;
        }
      }
      asm volatile("s_waitcnt lgkmcnt(0)" ::: "memory");
      for (int kk = 0; kk < 2; ++kk) {
        f16x8 pf = *(const f16x8*)(pls[wid] + kk * 1024 + lane * 16);
        for (int nt = 0; nt < 4; ++nt) {
          f16x8 vf = *(const f16x8*)(vcur + ((nt * 2 + kk) * 64 + lane) * 16);
          acc[nt] = __builtin_amdgcn_mfma_f32_16x16x32_f16(pf, vf, acc[nt], 0, 0, 0);
        }
        accs = __builtin_amdgcn_mfma_f32_16x16x32_f16(pf, onev, accs, 0, 0, 0);
      }
    }
    // epilogue: accs[r] holds lsum for q=qw+lq*4+r (same row layout as acc)
    for (int r = 0; r < 4; ++r) {
      float ir = 1.0f / accs[r];
      int t = qw + lq * 4 + r;
      for (int nt = 0; nt < 4; ++nt)
        ctx[((size_t)(b * T_SEQ + t) * DM) + h * DH + nt * 16 + lm] = f2h(acc[nt][r] * ir);
    }
  }
}

extern "C" void kernel_launch(void* const* d_in, const int* in_sizes, int n_in,
                              void* d_out, int out_size, void* d_ws, size_t ws_size,
                              hipStream_t stream) {
  const float* q = (const float*)d_in[0];
  const float* k = (const float*)d_in[1];
  const float* v = (const float*)d_in[2];
  const float* attn_mask = (const float*)d_in[3];
  const float* Wq = (const float*)d_in[4];
  const float* Wk = (const float*)d_in[5];
  const float* Wv = (const float*)d_in[6];
  const float* Wo = (const float*)d_in[7];
  const int* mf = (const int*)d_in[8];

  u16* ws = (u16*)d_ws;
  u16* qb  = ws;                      // f16 inputs [8192,1024] x3 (q,k,v contiguous)
  u16* wqb = ws + 3u * 8388608u;      // f16 weights x4
  u16* wkb = wqb + 1048576u;
  u16* wvb = wkb + 1048576u;
  u16* wob = wvb + 1048576u;
  u16* Qh  = wob + 1048576u;          // [bh][t][64]
  u16* Kh  = Qh + 8388608u;           // [bh][t][64]
  u16* VTh = Kh + 8388608u;           // [bh][dh][2048]
  u16* ctxb = ws;                     // alias over qb (dead after projections)

  convert_all<<<14336, 256, 0, stream>>>(q, k, v, Wq, Wk, Wv, Wo, qb, wqb);

  dim3 gq(32, 24);
  gemm_qkv<<<gq, 512, 0, stream>>>(qb, wqb, wkb, wvb, Qh, Kh, VTh);

  attn_kernel<<<512, 512, 0, stream>>>(Qh, Kh, VTh, attn_mask, mf, ctxb);

  dim3 gg(32, 8);
  gemm_out<<<gg, 512, 0, stream>>>(ctxb, wob, (float*)d_out);
}

// Round 8
// 337.773 us; speedup vs baseline: 1.0975x; 1.0269x over previous
//
#include <hip/hip_runtime.h>

typedef unsigned short u16;
typedef __attribute__((ext_vector_type(8))) _Float16 f16x8;
typedef __attribute__((ext_vector_type(2))) __fp16 fp16v2;
typedef __attribute__((ext_vector_type(4))) float f32x4;
typedef __attribute__((ext_vector_type(16))) float f32x16;

#define T_SEQ 2048
#define NH 16
#define DH 64
#define DM 1024
// NEG * log2(e), masks applied in log2 domain (softmax via exp2)
#define NEG2 (-14426.95f)
// 64^-0.25 * sqrt(log2(e)) : folded so S^T comes out pre-scaled for exp2
#define QS2 (0.42466089f)

__device__ __forceinline__ unsigned pk2(float a, float b) {
  union { fp16v2 v; unsigned u; } c;
  c.v = __builtin_amdgcn_cvt_pkrtz(a, b);
  return c.u;
}
__device__ __forceinline__ u16 f2h(float a) {
  union { _Float16 h; u16 u; } c; c.h = (_Float16)a; return c.u;
}

__device__ __forceinline__ void async_load16(const void* g, void* l) {
  __builtin_amdgcn_global_load_lds(
      (const __attribute__((address_space(1))) unsigned int*)(g),
      (__attribute__((address_space(3))) unsigned int*)(l), 16, 0, 0);
}

// ---------------- convert fp32 -> fp16 ----------------
__global__ __launch_bounds__(256) void convert_all(
    const float* __restrict__ q, const float* __restrict__ k, const float* __restrict__ v,
    const float* __restrict__ Wq, const float* __restrict__ Wk, const float* __restrict__ Wv,
    const float* __restrict__ Wo, u16* __restrict__ xb, u16* __restrict__ wb) {
  int blk = blockIdx.x;
  const float* src; u16* dst;
  if (blk < 12288) {
    int s = blk >> 12;
    src = (s == 0) ? q : (s == 1) ? k : v;
    dst = xb + (size_t)s * 8388608u;
    blk &= 4095;
  } else {
    int s = (blk - 12288) >> 9;
    src = (s == 0) ? Wq : (s == 1) ? Wk : (s == 2) ? Wv : Wo;
    dst = wb + (size_t)s * 1048576u;
    blk = (blk - 12288) & 511;
  }
  size_t base = (size_t)blk * 2048 + (size_t)threadIdx.x * 8;
  float4 a = *(const float4*)(src + base);
  float4 b2 = *(const float4*)(src + base + 4);
  uint4 st;
  st.x = pk2(a.x, a.y); st.y = pk2(a.z, a.w);
  st.z = pk2(b2.x, b2.y); st.w = pk2(b2.z, b2.w);
  *(uint4*)(dst + base) = st;
}

// ---------------- fused QKV projection GEMM: 256x128 tile, phase-split, counted vmcnt ----
// (unchanged -- passing)
__global__ __launch_bounds__(512) void gemm_qkv(const u16* __restrict__ A,
                                                const u16* __restrict__ Wqb,
                                                const u16* __restrict__ Wkb,
                                                const u16* __restrict__ Wvb,
                                                u16* __restrict__ Qh, u16* __restrict__ Kh,
                                                u16* __restrict__ VTh) {
  __shared__ char lds[147456];  // 3 x 48KB staging; epilogue tile aliases [0, ~68KB)
  const int tid = threadIdx.x;
  const int wid = tid >> 6, lane = tid & 63;
  const int l32 = lane & 31, lh = lane >> 5;
  const int m0 = blockIdx.x * 256;               // t rows
  const int n0 = blockIdx.y * 128;               // ch cols + which
  const int which = n0 >> 10;
  const int n0l = n0 & 1023;
  const u16* As = A + (size_t)which * 8388608u;
  const u16* Bw = (which == 0) ? Wqb : (which == 1) ? Wkb : Wvb;
  f32x16 acc[2][2] = {};

  const u16* gsrc[6]; int ldso[6];
#pragma unroll
  for (int u = 0; u < 6; ++u) {
    int c = wid * 6 + u;
    ldso[u] = c * 1024;
    if (c < 32)
      gsrc[u] = As + (size_t)(m0 + (c >> 2) * 32 + l32) * 1024 + (c & 3) * 16 + lh * 8;
    else {
      int cw = c - 32;
      gsrc[u] = Bw + (size_t)(n0l + (cw >> 2) * 32 + l32) * 1024 + (cw & 3) * 16 + lh * 8;
    }
  }

  const int rOff = (which < 2) ? 32768 : 0;   // Q/K: rows = W; V: rows = X
  const int cOff = 32768 - rOff;
  const int rgo = (which < 2) ? ((wid & 1) * 2) : ((wid >> 1) * 2);
  const int cgo = (which < 2) ? ((wid >> 1) * 2) : ((wid & 1) * 2);

#pragma unroll
  for (int u = 0; u < 6; ++u) async_load16(gsrc[u] + 0 * 64, lds + 0 * 49152 + ldso[u]);
#pragma unroll
  for (int u = 0; u < 6; ++u) async_load16(gsrc[u] + 1 * 64, lds + 1 * 49152 + ldso[u]);
  asm volatile("s_waitcnt vmcnt(6)" ::: "memory");
  __builtin_amdgcn_s_barrier();
  asm volatile("" ::: "memory");

  int slotc = 0, slotn = 2;
  for (int kt = 0; kt < 16; ++kt) {
    char* bufc = lds + slotc * 49152;
    char* bufn = lds + slotn * 49152;
    const char* rb = bufc + rOff;
    const char* cb = bufc + cOff;
    f16x8 a0[4], a1[4], b0[4], b1[4];
    // ---- Phase A ----
#pragma unroll
    for (int k = 0; k < 4; ++k) {
      a0[k] = *(const f16x8*)(rb + ((rgo + 0) * 4 + k) * 1024 + lane * 16);
      b0[k] = *(const f16x8*)(cb + ((cgo + 0) * 4 + k) * 1024 + lane * 16);
      b1[k] = *(const f16x8*)(cb + ((cgo + 1) * 4 + k) * 1024 + lane * 16);
    }
    if (kt < 14) {
#pragma unroll
      for (int u = 0; u < 3; ++u) async_load16(gsrc[u] + (kt + 2) * 64, bufn + ldso[u]);
    }
    asm volatile("" ::: "memory");
    __builtin_amdgcn_s_barrier();
    asm volatile("s_waitcnt lgkmcnt(0)" ::: "memory");
    __builtin_amdgcn_sched_barrier(0);
    __builtin_amdgcn_s_setprio(1);
#pragma unroll
    for (int k = 0; k < 4; ++k) {
      acc[0][0] = __builtin_amdgcn_mfma_f32_32x32x16_f16(a0[k], b0[k], acc[0][0], 0, 0, 0);
      acc[0][1] = __builtin_amdgcn_mfma_f32_32x32x16_f16(a0[k], b1[k], acc[0][1], 0, 0, 0);
    }
    __builtin_amdgcn_s_setprio(0);
    asm volatile("" ::: "memory");
    __builtin_amdgcn_s_barrier();
    // ---- Phase B ----
#pragma unroll
    for (int k = 0; k < 4; ++k)
      a1[k] = *(const f16x8*)(rb + ((rgo + 1) * 4 + k) * 1024 + lane * 16);
    if (kt < 14) {
#pragma unroll
      for (int u = 3; u < 6; ++u) async_load16(gsrc[u] + (kt + 2) * 64, bufn + ldso[u]);
    }
    if (kt < 14) asm volatile("s_waitcnt vmcnt(6)" ::: "memory");
    else         asm volatile("s_waitcnt vmcnt(0)" ::: "memory");
    asm volatile("" ::: "memory");
    __builtin_amdgcn_s_barrier();
    asm volatile("s_waitcnt lgkmcnt(0)" ::: "memory");
    __builtin_amdgcn_sched_barrier(0);
    __builtin_amdgcn_s_setprio(1);
#pragma unroll
    for (int k = 0; k < 4; ++k) {
      acc[1][0] = __builtin_amdgcn_mfma_f32_32x32x16_f16(a1[k], b0[k], acc[1][0], 0, 0, 0);
      acc[1][1] = __builtin_amdgcn_mfma_f32_32x32x16_f16(a1[k], b1[k], acc[1][1], 0, 0, 0);
    }
    __builtin_amdgcn_s_setprio(0);
    asm volatile("" ::: "memory");
    __builtin_amdgcn_s_barrier();
    slotc = (slotc == 2) ? 0 : slotc + 1;
    slotn = (slotn == 2) ? 0 : slotn + 1;
  }

  // epilogue. C/D 32x32: col = l32, row = (reg&3)+8*(reg>>2)+4*lh.
  const float s = (which < 2) ? QS2 : 1.0f;
  const int b = m0 >> 11, t0 = m0 & 2047, h0 = n0l >> 6;
  __syncthreads();  // full drain before aliasing staging LDS
  if (which < 2) {
#pragma unroll
    for (int i = 0; i < 2; ++i)
#pragma unroll
      for (int j = 0; j < 2; ++j) {
        int colb = (wid >> 1) * 64 + j * 32 + l32;   // t_local
        int rowb = (wid & 1) * 64 + i * 32 + 4 * lh; // ch base
#pragma unroll
        for (int g = 0; g < 4; ++g) {
          uint2 pv;
          pv.x = pk2(acc[i][j][4 * g + 0] * s, acc[i][j][4 * g + 1] * s);
          pv.y = pk2(acc[i][j][4 * g + 2] * s, acc[i][j][4 * g + 3] * s);
          *(uint2*)(lds + colb * 264 + (rowb + 8 * g) * 2) = pv;
        }
      }
    __syncthreads();
    u16* O = which ? Kh : Qh;
#pragma unroll
    for (int p = 0; p < 8; ++p) {
      int row = p * 32 + (tid >> 4);  // t_local 0..255
      int seg = tid & 15;
      uint4 val = *(const uint4*)(lds + row * 264 + seg * 16);
      int hl = seg >> 3, dh0 = (seg & 7) * 8;
      *(uint4*)(O + (((size_t)(b * NH + h0 + hl) * T_SEQ + t0 + row) << 6) + dh0) = val;
    }
  } else {
#pragma unroll
    for (int i = 0; i < 2; ++i)
#pragma unroll
      for (int j = 0; j < 2; ++j) {
        int colb = (wid & 1) * 64 + j * 32 + l32;    // ch_local
        int rowb = (wid >> 1) * 64 + i * 32 + 4 * lh; // t base
#pragma unroll
        for (int g = 0; g < 4; ++g) {
          uint2 pv;
          pv.x = pk2(acc[i][j][4 * g + 0], acc[i][j][4 * g + 1]);
          pv.y = pk2(acc[i][j][4 * g + 2], acc[i][j][4 * g + 3]);
          *(uint2*)(lds + colb * 520 + (rowb + 8 * g) * 2) = pv;
        }
      }
    __syncthreads();
#pragma unroll
    for (int p = 0; p < 8; ++p) {
      int row = p * 16 + (tid >> 5);  // ch_local 0..127
      int seg = tid & 31;
      uint4 val = *(const uint4*)(lds + row * 520 + seg * 16);
      int h = h0 + (row >> 6), dh = row & 63;
      *(uint4*)(VTh + (((size_t)(b * NH + h) * DH + dh) << 11) + t0 + seg * 8) = val;
    }
  }
}

// ---------------- output projection GEMM: 256x128 tile, phase-split, counted vmcnt ----
// (unchanged -- passing)
__global__ __launch_bounds__(512) void gemm_out(const u16* __restrict__ A,
                                                const u16* __restrict__ Bw,
                                                float* __restrict__ O) {
  __shared__ char lds[147456];
  const int tid = threadIdx.x;
  const int wid = tid >> 6, lane = tid & 63;
  const int l32 = lane & 31, lh = lane >> 5;
  const int m0 = blockIdx.x * 256, n0 = blockIdx.y * 128;
  f32x16 acc[2][2] = {};

  const u16* gsrc[6]; int ldso[6];
#pragma unroll
  for (int u = 0; u < 6; ++u) {
    int c = wid * 6 + u;
    ldso[u] = c * 1024;
    if (c < 32)
      gsrc[u] = A + (size_t)(m0 + (c >> 2) * 32 + l32) * 1024 + (c & 3) * 16 + lh * 8;
    else {
      int cw = c - 32;
      gsrc[u] = Bw + (size_t)(n0 + (cw >> 2) * 32 + l32) * 1024 + (cw & 3) * 16 + lh * 8;
    }
  }
  const int rgo = (wid >> 1) * 2, cgo = (wid & 1) * 2;

#pragma unroll
  for (int u = 0; u < 6; ++u) async_load16(gsrc[u] + 0 * 64, lds + 0 * 49152 + ldso[u]);
#pragma unroll
  for (int u = 0; u < 6; ++u) async_load16(gsrc[u] + 1 * 64, lds + 1 * 49152 + ldso[u]);
  asm volatile("s_waitcnt vmcnt(6)" ::: "memory");
  __builtin_amdgcn_s_barrier();
  asm volatile("" ::: "memory");

  int slotc = 0, slotn = 2;
  for (int kt = 0; kt < 16; ++kt) {
    char* bufc = lds + slotc * 49152;
    char* bufn = lds + slotn * 49152;
    const char* rb = bufc;           // X region (rows = t)
    const char* cb = bufc + 32768;   // W region (rows = e)
    f16x8 a0[4], a1[4], b0[4], b1[4];
    // ---- Phase A ----
#pragma unroll
    for (int k = 0; k < 4; ++k) {
      a0[k] = *(const f16x8*)(rb + ((rgo + 0) * 4 + k) * 1024 + lane * 16);
      b0[k] = *(const f16x8*)(cb + ((cgo + 0) * 4 + k) * 1024 + lane * 16);
      b1[k] = *(const f16x8*)(cb + ((cgo + 1) * 4 + k) * 1024 + lane * 16);
    }
    if (kt < 14) {
#pragma unroll
      for (int u = 0; u < 3; ++u) async_load16(gsrc[u] + (kt + 2) * 64, bufn + ldso[u]);
    }
    asm volatile("" ::: "memory");
    __builtin_amdgcn_s_barrier();
    asm volatile("s_waitcnt lgkmcnt(0)" ::: "memory");
    __builtin_amdgcn_sched_barrier(0);
    __builtin_amdgcn_s_setprio(1);
#pragma unroll
    for (int k = 0; k < 4; ++k) {
      acc[0][0] = __builtin_amdgcn_mfma_f32_32x32x16_f16(a0[k], b0[k], acc[0][0], 0, 0, 0);
      acc[0][1] = __builtin_amdgcn_mfma_f32_32x32x16_f16(a0[k], b1[k], acc[0][1], 0, 0, 0);
    }
    __builtin_amdgcn_s_setprio(0);
    asm volatile("" ::: "memory");
    __builtin_amdgcn_s_barrier();
    // ---- Phase B ----
#pragma unroll
    for (int k = 0; k < 4; ++k)
      a1[k] = *(const f16x8*)(rb + ((rgo + 1) * 4 + k) * 1024 + lane * 16);
    if (kt < 14) {
#pragma unroll
      for (int u = 3; u < 6; ++u) async_load16(gsrc[u] + (kt + 2) * 64, bufn + ldso[u]);
    }
    if (kt < 14) asm volatile("s_waitcnt vmcnt(6)" ::: "memory");
    else         asm volatile("s_waitcnt vmcnt(0)" ::: "memory");
    asm volatile("" ::: "memory");
    __builtin_amdgcn_s_barrier();
    asm volatile("s_waitcnt lgkmcnt(0)" ::: "memory");
    __builtin_amdgcn_sched_barrier(0);
    __builtin_amdgcn_s_setprio(1);
#pragma unroll
    for (int k = 0; k < 4; ++k) {
      acc[1][0] = __builtin_amdgcn_mfma_f32_32x32x16_f16(a1[k], b0[k], acc[1][0], 0, 0, 0);
      acc[1][1] = __builtin_amdgcn_mfma_f32_32x32x16_f16(a1[k], b1[k], acc[1][1], 0, 0, 0);
    }
    __builtin_amdgcn_s_setprio(0);
    asm volatile("" ::: "memory");
    __builtin_amdgcn_s_barrier();
    slotc = (slotc == 2) ? 0 : slotc + 1;
    slotn = (slotn == 2) ? 0 : slotn + 1;
  }
  // epilogue: direct fp32 stores. row = rowb + 8*g + rr, col contiguous over l32.
#pragma unroll
  for (int i = 0; i < 2; ++i)
#pragma unroll
    for (int j = 0; j < 2; ++j) {
      int col = n0 + (wid & 1) * 64 + j * 32 + l32;
      int rowb = m0 + (wid >> 1) * 64 + i * 32 + 4 * lh;
#pragma unroll
      for (int g = 0; g < 4; ++g)
#pragma unroll
        for (int rr = 0; rr < 4; ++rr)
          O[(size_t)(rowb + 8 * g + rr) * 1024 + col] = acc[i][j][4 * g + rr];
    }
}

// ---------------- Flash attention (S^T formulation, fp16, 8 waves) ----------------
// Round-8 change: ONE q-tile per block (no pair loop). Grid 1024 = 4 blocks/CU
// available; LDS 49.7KB caps residency at 3 (was grid-capped at 2). q-tiles
// dispatched in DESCENDING work order (qt = 15 - (bid>>6)) so long causal
// blocks start first and short ones backfill. bh = bid&63 keeps the XCD
// affinity (bid&7 == bh&7). Body identical to round 7 otherwise.
__global__ __launch_bounds__(512) void attn_kernel(const u16* __restrict__ Qh,
                                                   const u16* __restrict__ Kh,
                                                   const u16* __restrict__ VTh,
                                                   const float* __restrict__ attn_mask,
                                                   const int* __restrict__ mfp,
                                                   u16* __restrict__ ctx) {
  __shared__ char kls[2][8192];   // K chunk (64s x 64k), cells (st*2+kk), x2 dbuf
  __shared__ char vls[2][8192];   // V^T chunk (64dh x 64s), cells (nt*2+kk), x2 dbuf
  __shared__ char pls[8][2048];   // per-wave P (16q x 64s) in A-frag order
  __shared__ int mzf;             // 1 if any pad-mask zero for this b

  const int tid = threadIdx.x;
  const int wid = tid >> 6, lane = tid & 63;
  const int lm = lane & 15, lq = lane >> 4;
  const int bid = blockIdx.x;
  const int bh_i = bid & 63;
  const int qt = 15 - (bid >> 6);         // descending work order
  const int b = bh_i >> 4, h = bh_i & 15;
  const int mf = *mfp;
  const size_t bh = (size_t)(b * NH + h);
  const u16* Qbh = Qh + bh * T_SEQ * DH;
  const u16* Kbh = Kh + bh * T_SEQ * DH;
  const u16* VTbh = VTh + bh * DH * T_SEQ;
  const float* amb = attn_mask + (size_t)b * T_SEQ;

  f16x8 onev;
#pragma unroll
  for (int i = 0; i < 8; ++i) onev[i] = (_Float16)1.0f;

  if (tid == 0) mzf = 0;
  __syncthreads();
  {
    int az = 0;
    for (int i = tid; i < T_SEQ; i += 512) az |= (amb[i] == 0.0f);
    if (az) mzf = 1;  // benign same-value race
  }
  __syncthreads();
  const int maskzero = mzf;

  const int qw = qt * 128 + wid * 16;
  f16x8 qf[2];
  qf[0] = *(const f16x8*)(Qbh + (size_t)(qw + lm) * DH + lq * 8);
  qf[1] = *(const f16x8*)(Qbh + (size_t)(qw + lm) * DH + 32 + lq * 8);

  f32x4 acc[4] = {};
  f32x4 accs = {};                 // row-sum accumulator: accs[r] = lsum(q=lq*4+r)
  float mprev = -1e30f;

  const int nch = mf ? (qt + 1) * 2 : 32;
  {
    async_load16(Kbh + (size_t)((wid >> 1) * 16 + lm) * DH + (wid & 1) * 32 + lq * 8,
                 kls[0] + wid * 1024);
    async_load16(VTbh + (size_t)((wid >> 1) * 16 + lm) * T_SEQ + (wid & 1) * 32 + lq * 8,
                 vls[0] + wid * 1024);
  }
  for (int c = 0; c < nch; ++c) {
    const int s0 = c * 64;
    asm volatile("s_waitcnt vmcnt(0)" ::: "memory");
    __builtin_amdgcn_s_barrier();
    asm volatile("" ::: "memory");
    if (c + 1 < nch) {
      const int s1 = s0 + 64;
      async_load16(Kbh + (size_t)(s1 + (wid >> 1) * 16 + lm) * DH + (wid & 1) * 32 + lq * 8,
                   kls[(c + 1) & 1] + wid * 1024);
      async_load16(VTbh + (size_t)((wid >> 1) * 16 + lm) * T_SEQ + s1 + (wid & 1) * 32 + lq * 8,
                   vls[(c + 1) & 1] + wid * 1024);
    }
    const char* kcur = kls[c & 1];
    const char* vcur = vls[c & 1];

    f32x4 sc[4];
    for (int st = 0; st < 4; ++st) {
      f32x4 z = {0.f, 0.f, 0.f, 0.f};
      sc[st] = z;
      for (int kk = 0; kk < 2; ++kk) {
        f16x8 kf = *(const f16x8*)(kcur + ((st * 2 + kk) * 64 + lane) * 16);
        sc[st] = __builtin_amdgcn_mfma_f32_16x16x32_f16(kf, qf[kk], sc[st], 0, 0, 0);
      }
    }
    if (maskzero) {  // rare path: pad bias straight from global (L2-resident)
      for (int st = 0; st < 4; ++st) {
        f32x4 mb = *(const f32x4*)(amb + s0 + st * 16 + lq * 4);
        for (int r = 0; r < 4; ++r)
          if (mb[r] == 0.0f) sc[st][r] += NEG2;
      }
    }
    if (mf && (s0 + 64 > qw)) {
      int qg = qw + lm;
      for (int st = 0; st < 4; ++st)
        for (int r = 0; r < 4; ++r)
          if (s0 + st * 16 + lq * 4 + r > qg) sc[st][r] = NEG2;
    }
    // chunk max via max3-shaped tree (8 ops)
    float u0 = fmaxf(fmaxf(sc[0][0], sc[0][1]), sc[0][2]);
    float u1 = fmaxf(fmaxf(sc[0][3], sc[1][0]), sc[1][1]);
    float u2 = fmaxf(fmaxf(sc[1][2], sc[1][3]), sc[2][0]);
    float u3 = fmaxf(fmaxf(sc[2][1], sc[2][2]), sc[2][3]);
    float u4 = fmaxf(fmaxf(sc[3][0], sc[3][1]), sc[3][2]);
    float mx = fmaxf(fmaxf(fmaxf(u0, u1), u2), fmaxf(fmaxf(u3, u4), sc[3][3]));
    mx = fmaxf(mx, __shfl_xor(mx, 16));
    mx = fmaxf(mx, __shfl_xor(mx, 32));
    // defer-max: rescale only when the max grew by more than THR=8 (log2 domain)
    if (__ballot(mx > mprev + 8.0f) != 0ull) {
      float mn2 = fmaxf(mprev, mx);
      float alpha = exp2f(mprev - mn2);
      for (int r = 0; r < 4; ++r) {
        float ar = __shfl(alpha, lq * 4 + r);
        for (int nt = 0; nt < 4; ++nt) acc[nt][r] *= ar;
        accs[r] *= ar;
      }
      mprev = mn2;
    }
    for (int st = 0; st < 4; ++st)
      for (int r = 0; r < 4; ++r)
        sc[st][r] = exp2f(sc[st][r] - mprev);
    {
      char* pw = pls[wid];
      for (int st = 0; st < 4; ++st) {
        int kk = st >> 1;
        int lqp = (st & 1) * 2 + (lq >> 1);
        uint2 pv;
        pv.x = pk2(sc[st][0], sc[st][1]);
        pv.y = pk2(sc[st][2], sc[st][3]);
        *(uint2*)(pw + kk * 1024 + (lqp * 16 + lm) * 16 + (lq & 1) * 8) = pv;
      }
    }
    asm volatile("s_waitcnt lgkmcnt(0)" ::: "memory");
    for (int kk = 0; kk < 2; ++kk) {
      f16x8 pf = *(const f16x8*)(pls[wid] + kk * 1024 + lane * 16);
      for (int nt = 0; nt < 4; ++nt) {
        f16x8 vf = *(const f16x8*)(vcur + ((nt * 2 + kk) * 64 + lane) * 16);
        acc[nt] = __builtin_amdgcn_mfma_f32_16x16x32_f16(pf, vf, acc[nt], 0, 0, 0);
      }
      accs = __builtin_amdgcn_mfma_f32_16x16x32_f16(pf, onev, accs, 0, 0, 0);
    }
  }
  // epilogue: accs[r] holds lsum for q=qw+lq*4+r (same row layout as acc)
  for (int r = 0; r < 4; ++r) {
    float ir = 1.0f / accs[r];
    int t = qw + lq * 4 + r;
    for (int nt = 0; nt < 4; ++nt)
      ctx[((size_t)(b * T_SEQ + t) * DM) + h * DH + nt * 16 + lm] = f2h(acc[nt][r] * ir);
  }
}

extern "C" void kernel_launch(void* const* d_in, const int* in_sizes, int n_in,
                              void* d_out, int out_size, void* d_ws, size_t ws_size,
                              hipStream_t stream) {
  const float* q = (const float*)d_in[0];
  const float* k = (const float*)d_in[1];
  const float* v = (const float*)d_in[2];
  const float* attn_mask = (const float*)d_in[3];
  const float* Wq = (const float*)d_in[4];
  const float* Wk = (const float*)d_in[5];
  const float* Wv = (const float*)d_in[6];
  const float* Wo = (const float*)d_in[7];
  const int* mf = (const int*)d_in[8];

  u16* ws = (u16*)d_ws;
  u16* qb  = ws;                      // f16 inputs [8192,1024] x3 (q,k,v contiguous)
  u16* wqb = ws + 3u * 8388608u;      // f16 weights x4
  u16* wkb = wqb + 1048576u;
  u16* wvb = wkb + 1048576u;
  u16* wob = wvb + 1048576u;
  u16* Qh  = wob + 1048576u;          // [bh][t][64]
  u16* Kh  = Qh + 8388608u;           // [bh][t][64]
  u16* VTh = Kh + 8388608u;           // [bh][dh][2048]
  u16* ctxb = ws;                     // alias over qb (dead after projections)

  convert_all<<<14336, 256, 0, stream>>>(q, k, v, Wq, Wk, Wv, Wo, qb, wqb);

  dim3 gq(32, 24);
  gemm_qkv<<<gq, 512, 0, stream>>>(qb, wqb, wkb, wvb, Qh, Kh, VTh);

  attn_kernel<<<1024, 512, 0, stream>>>(Qh, Kh, VTh, attn_mask, mf, ctxb);

  dim3 gg(32, 8);
  gemm_out<<<gg, 512, 0, stream>>>(ctxb, wob, (float*)d_out);
}

// Round 9
// 331.565 us; speedup vs baseline: 1.1181x; 1.0187x over previous
//
#include <hip/hip_runtime.h>

typedef unsigned short u16;
typedef __attribute__((ext_vector_type(8))) _Float16 f16x8;
typedef __attribute__((ext_vector_type(2))) __fp16 fp16v2;
typedef __attribute__((ext_vector_type(4))) float f32x4;
typedef __attribute__((ext_vector_type(16))) float f32x16;

#define T_SEQ 2048
#define NH 16
#define DH 64
#define DM 1024
// NEG * log2(e), masks applied in log2 domain (softmax via exp2)
#define NEG2 (-14426.95f)
// 64^-0.25 * sqrt(log2(e)) : folded so S^T comes out pre-scaled for exp2
#define QS2 (0.42466089f)

__device__ __forceinline__ unsigned pk2(float a, float b) {
  union { fp16v2 v; unsigned u; } c;
  c.v = __builtin_amdgcn_cvt_pkrtz(a, b);
  return c.u;
}
__device__ __forceinline__ u16 f2h(float a) {
  union { _Float16 h; u16 u; } c; c.h = (_Float16)a; return c.u;
}

__device__ __forceinline__ void async_load16(const void* g, void* l) {
  __builtin_amdgcn_global_load_lds(
      (const __attribute__((address_space(1))) unsigned int*)(g),
      (__attribute__((address_space(3))) unsigned int*)(l), 16, 0, 0);
}

// ---------------- convert fp32 -> fp16 ----------------
__global__ __launch_bounds__(256) void convert_all(
    const float* __restrict__ q, const float* __restrict__ k, const float* __restrict__ v,
    const float* __restrict__ Wq, const float* __restrict__ Wk, const float* __restrict__ Wv,
    const float* __restrict__ Wo, u16* __restrict__ xb, u16* __restrict__ wb) {
  int blk = blockIdx.x;
  const float* src; u16* dst;
  if (blk < 12288) {
    int s = blk >> 12;
    src = (s == 0) ? q : (s == 1) ? k : v;
    dst = xb + (size_t)s * 8388608u;
    blk &= 4095;
  } else {
    int s = (blk - 12288) >> 9;
    src = (s == 0) ? Wq : (s == 1) ? Wk : (s == 2) ? Wv : Wo;
    dst = wb + (size_t)s * 1048576u;
    blk = (blk - 12288) & 511;
  }
  size_t base = (size_t)blk * 2048 + (size_t)threadIdx.x * 8;
  float4 a = *(const float4*)(src + base);
  float4 b2 = *(const float4*)(src + base + 4);
  uint4 st;
  st.x = pk2(a.x, a.y); st.y = pk2(a.z, a.w);
  st.z = pk2(b2.x, b2.y); st.w = pk2(b2.z, b2.w);
  *(uint4*)(dst + base) = st;
}

// ---------------- fused QKV projection GEMM: 256x128 tile, BK=32, 2 blocks/CU ----
// which selects input activation/weight/output. 8 waves; per-wave 64x64 out.
// LDS: 3 buffers x 24KB (X-tile 16KB = cells 0..15, W-tile 8KB = cells 16..23),
// cell = 1KB [l32 row][lh*8 col] (32 rows x 16 u16); wave stages 3 cells/K-tile.
// K-loop: ONE barrier per K-tile (r2-proven tri-buffer invariant):
//   vmcnt(3) [own tile-kt loads landed; kt+1's stay in flight] | barrier |
//   prefetch kt+2 -> buf freed at kt-1 | issue 8 ds_reads | MFMA ks0 | MFMA ks1
// Compiler emits fine-grained lgkm waits, so ks1 reads drain under ks0 MFMAs.
// 72KB LDS -> 2 blocks/CU resident (grid 768 = 3/CU): one block's LDS burst
// overlaps the other's MFMA cluster.
__global__ __launch_bounds__(512) void gemm_qkv(const u16* __restrict__ A,
                                                const u16* __restrict__ Wqb,
                                                const u16* __restrict__ Wkb,
                                                const u16* __restrict__ Wvb,
                                                u16* __restrict__ Qh, u16* __restrict__ Kh,
                                                u16* __restrict__ VTh) {
  __shared__ char lds[73728];  // 3 x 24KB staging; epilogue tile aliases [0, ~68KB)
  const int tid = threadIdx.x;
  const int wid = tid >> 6, lane = tid & 63;
  const int l32 = lane & 31, lh = lane >> 5;
  const int m0 = blockIdx.x * 256;               // t rows
  const int n0 = blockIdx.y * 128;               // ch cols + which
  const int which = n0 >> 10;
  const int n0l = n0 & 1023;
  const u16* As = A + (size_t)which * 8388608u;
  const u16* Bw = (which == 0) ? Wqb : (which == 1) ? Wkb : Wvb;
  f32x16 acc[2][2] = {};

  // staging: cell c = wid*3+u. c<16: X cell (row m0+(c>>1)*32+l32, col (c&1)*16);
  // c>=16: W cell cw=c-16 (row n0l+(cw>>1)*32+l32, col (cw&1)*16). +kt*32 per tile.
  const u16* gsrc[3]; int ldso[3];
#pragma unroll
  for (int u = 0; u < 3; ++u) {
    int c = wid * 3 + u;
    ldso[u] = c * 1024;
    if (c < 16)
      gsrc[u] = As + (size_t)(m0 + (c >> 1) * 32 + l32) * 1024 + (c & 1) * 16 + lh * 8;
    else {
      int cw = c - 16;
      gsrc[u] = Bw + (size_t)(n0l + (cw >> 1) * 32 + l32) * 1024 + (cw & 1) * 16 + lh * 8;
    }
  }

  const int rOff = (which < 2) ? 16384 : 0;   // Q/K: rows = W; V: rows = X
  const int cOff = 16384 - rOff;
  const int rgo = (which < 2) ? ((wid & 1) * 2) : ((wid >> 1) * 2);
  const int cgo = (which < 2) ? ((wid >> 1) * 2) : ((wid & 1) * 2);

  // prologue: stage tiles 0,1 into buffers 0,1 (6 loads/wave in flight)
#pragma unroll
  for (int u = 0; u < 3; ++u) async_load16(gsrc[u] + 0 * 32, lds + 0 * 24576 + ldso[u]);
#pragma unroll
  for (int u = 0; u < 3; ++u) async_load16(gsrc[u] + 1 * 32, lds + 1 * 24576 + ldso[u]);

  int slotc = 0, slotn = 2;
  for (int kt = 0; kt < 32; ++kt) {
    if (kt < 31) asm volatile("s_waitcnt vmcnt(3)" ::: "memory");
    else         asm volatile("s_waitcnt vmcnt(0)" ::: "memory");
    __builtin_amdgcn_s_barrier();   // all waves' tile-kt loads landed; buf (kt+2)%3 free
    asm volatile("" ::: "memory");  // pin LDS ops below the barrier
    char* bufc = lds + slotc * 24576;
    if (kt < 30) {
      char* bufn = lds + slotn * 24576;
      int ko = (kt + 2) * 32;
#pragma unroll
      for (int u = 0; u < 3; ++u) async_load16(gsrc[u] + ko, bufn + ldso[u]);
    }
    const char* rb = bufc + rOff;
    const char* cb = bufc + cOff;
    f16x8 r0[2], c0[2], r1[2], c1[2];
#pragma unroll
    for (int i = 0; i < 2; ++i) {
      r0[i] = *(const f16x8*)(rb + ((rgo + i) * 2 + 0) * 1024 + lane * 16);
      c0[i] = *(const f16x8*)(cb + ((cgo + i) * 2 + 0) * 1024 + lane * 16);
    }
#pragma unroll
    for (int i = 0; i < 2; ++i) {
      r1[i] = *(const f16x8*)(rb + ((rgo + i) * 2 + 1) * 1024 + lane * 16);
      c1[i] = *(const f16x8*)(cb + ((cgo + i) * 2 + 1) * 1024 + lane * 16);
    }
    __builtin_amdgcn_s_setprio(1);
#pragma unroll
    for (int i = 0; i < 2; ++i)
#pragma unroll
      for (int j = 0; j < 2; ++j)
        acc[i][j] = __builtin_amdgcn_mfma_f32_32x32x16_f16(r0[i], c0[j], acc[i][j], 0, 0, 0);
#pragma unroll
    for (int i = 0; i < 2; ++i)
#pragma unroll
      for (int j = 0; j < 2; ++j)
        acc[i][j] = __builtin_amdgcn_mfma_f32_32x32x16_f16(r1[i], c1[j], acc[i][j], 0, 0, 0);
    __builtin_amdgcn_s_setprio(0);
    slotc = (slotc == 2) ? 0 : slotc + 1;
    slotn = (slotn == 2) ? 0 : slotn + 1;
  }

  // epilogue. C/D 32x32: col = l32, row = (reg&3)+8*(reg>>2)+4*lh. (unchanged)
  const float s = (which < 2) ? QS2 : 1.0f;
  const int b = m0 >> 11, t0 = m0 & 2047, h0 = n0l >> 6;
  __syncthreads();  // full drain before aliasing staging LDS
  if (which < 2) {
#pragma unroll
    for (int i = 0; i < 2; ++i)
#pragma unroll
      for (int j = 0; j < 2; ++j) {
        int colb = (wid >> 1) * 64 + j * 32 + l32;   // t_local
        int rowb = (wid & 1) * 64 + i * 32 + 4 * lh; // ch base
#pragma unroll
        for (int g = 0; g < 4; ++g) {
          uint2 pv;
          pv.x = pk2(acc[i][j][4 * g + 0] * s, acc[i][j][4 * g + 1] * s);
          pv.y = pk2(acc[i][j][4 * g + 2] * s, acc[i][j][4 * g + 3] * s);
          *(uint2*)(lds + colb * 264 + (rowb + 8 * g) * 2) = pv;
        }
      }
    __syncthreads();
    u16* O = which ? Kh : Qh;
#pragma unroll
    for (int p = 0; p < 8; ++p) {
      int row = p * 32 + (tid >> 4);  // t_local 0..255
      int seg = tid & 15;
      uint4 val = *(const uint4*)(lds + row * 264 + seg * 16);
      int hl = seg >> 3, dh0 = (seg & 7) * 8;
      *(uint4*)(O + (((size_t)(b * NH + h0 + hl) * T_SEQ + t0 + row) << 6) + dh0) = val;
    }
  } else {
#pragma unroll
    for (int i = 0; i < 2; ++i)
#pragma unroll
      for (int j = 0; j < 2; ++j) {
        int colb = (wid & 1) * 64 + j * 32 + l32;    // ch_local
        int rowb = (wid >> 1) * 64 + i * 32 + 4 * lh; // t base
#pragma unroll
        for (int g = 0; g < 4; ++g) {
          uint2 pv;
          pv.x = pk2(acc[i][j][4 * g + 0], acc[i][j][4 * g + 1]);
          pv.y = pk2(acc[i][j][4 * g + 2], acc[i][j][4 * g + 3]);
          *(uint2*)(lds + colb * 520 + (rowb + 8 * g) * 2) = pv;
        }
      }
    __syncthreads();
#pragma unroll
    for (int p = 0; p < 8; ++p) {
      int row = p * 16 + (tid >> 5);  // ch_local 0..127
      int seg = tid & 31;
      uint4 val = *(const uint4*)(lds + row * 520 + seg * 16);
      int h = h0 + (row >> 6), dh = row & 63;
      *(uint4*)(VTh + (((size_t)(b * NH + h) * DH + dh) << 11) + t0 + seg * 8) = val;
    }
  }
}

// ---------------- output projection GEMM: same 256x128/BK=32 single-barrier template ----
__global__ __launch_bounds__(512) void gemm_out(const u16* __restrict__ A,
                                                const u16* __restrict__ Bw,
                                                float* __restrict__ O) {
  __shared__ char lds[73728];
  const int tid = threadIdx.x;
  const int wid = tid >> 6, lane = tid & 63;
  const int l32 = lane & 31, lh = lane >> 5;
  const int m0 = blockIdx.x * 256, n0 = blockIdx.y * 128;
  f32x16 acc[2][2] = {};

  const u16* gsrc[3]; int ldso[3];
#pragma unroll
  for (int u = 0; u < 3; ++u) {
    int c = wid * 3 + u;
    ldso[u] = c * 1024;
    if (c < 16)
      gsrc[u] = A + (size_t)(m0 + (c >> 1) * 32 + l32) * 1024 + (c & 1) * 16 + lh * 8;
    else {
      int cw = c - 16;
      gsrc[u] = Bw + (size_t)(n0 + (cw >> 1) * 32 + l32) * 1024 + (cw & 1) * 16 + lh * 8;
    }
  }
  const int rgo = (wid >> 1) * 2, cgo = (wid & 1) * 2;

#pragma unroll
  for (int u = 0; u < 3; ++u) async_load16(gsrc[u] + 0 * 32, lds + 0 * 24576 + ldso[u]);
#pragma unroll
  for (int u = 0; u < 3; ++u) async_load16(gsrc[u] + 1 * 32, lds + 1 * 24576 + ldso[u]);

  int slotc = 0, slotn = 2;
  for (int kt = 0; kt < 32; ++kt) {
    if (kt < 31) asm volatile("s_waitcnt vmcnt(3)" ::: "memory");
    else         asm volatile("s_waitcnt vmcnt(0)" ::: "memory");
    __builtin_amdgcn_s_barrier();
    asm volatile("" ::: "memory");
    char* bufc = lds + slotc * 24576;
    if (kt < 30) {
      char* bufn = lds + slotn * 24576;
      int ko = (kt + 2) * 32;
#pragma unroll
      for (int u = 0; u < 3; ++u) async_load16(gsrc[u] + ko, bufn + ldso[u]);
    }
    const char* rb = bufc;           // X region (rows = t)
    const char* cb = bufc + 16384;   // W region (rows = e)
    f16x8 r0[2], c0[2], r1[2], c1[2];
#pragma unroll
    for (int i = 0; i < 2; ++i) {
      r0[i] = *(const f16x8*)(rb + ((rgo + i) * 2 + 0) * 1024 + lane * 16);
      c0[i] = *(const f16x8*)(cb + ((cgo + i) * 2 + 0) * 1024 + lane * 16);
    }
#pragma unroll
    for (int i = 0; i < 2; ++i) {
      r1[i] = *(const f16x8*)(rb + ((rgo + i) * 2 + 1) * 1024 + lane * 16);
      c1[i] = *(const f16x8*)(cb + ((cgo + i) * 2 + 1) * 1024 + lane * 16);
    }
    __builtin_amdgcn_s_setprio(1);
#pragma unroll
    for (int i = 0; i < 2; ++i)
#pragma unroll
      for (int j = 0; j < 2; ++j)
        acc[i][j] = __builtin_amdgcn_mfma_f32_32x32x16_f16(r0[i], c0[j], acc[i][j], 0, 0, 0);
#pragma unroll
    for (int i = 0; i < 2; ++i)
#pragma unroll
      for (int j = 0; j < 2; ++j)
        acc[i][j] = __builtin_amdgcn_mfma_f32_32x32x16_f16(r1[i], c1[j], acc[i][j], 0, 0, 0);
    __builtin_amdgcn_s_setprio(0);
    slotc = (slotc == 2) ? 0 : slotc + 1;
    slotn = (slotn == 2) ? 0 : slotn + 1;
  }
  // epilogue: direct fp32 stores. row = rowb + 8*g + rr, col contiguous over l32.
#pragma unroll
  for (int i = 0; i < 2; ++i)
#pragma unroll
    for (int j = 0; j < 2; ++j) {
      int col = n0 + (wid & 1) * 64 + j * 32 + l32;
      int rowb = m0 + (wid >> 1) * 64 + i * 32 + 4 * lh;
#pragma unroll
      for (int g = 0; g < 4; ++g)
#pragma unroll
        for (int rr = 0; rr < 4; ++rr)
          O[(size_t)(rowb + 8 * g + rr) * 1024 + col] = acc[i][j][4 * g + rr];
    }
}

// ---------------- Flash attention (S^T formulation, fp16, 8 waves) ----------------
// (unchanged from round 8 -- passing: one q-tile/block, grid 1024, 3 blocks/CU)
__global__ __launch_bounds__(512) void attn_kernel(const u16* __restrict__ Qh,
                                                   const u16* __restrict__ Kh,
                                                   const u16* __restrict__ VTh,
                                                   const float* __restrict__ attn_mask,
                                                   const int* __restrict__ mfp,
                                                   u16* __restrict__ ctx) {
  __shared__ char kls[2][8192];   // K chunk (64s x 64k), cells (st*2+kk), x2 dbuf
  __shared__ char vls[2][8192];   // V^T chunk (64dh x 64s), cells (nt*2+kk), x2 dbuf
  __shared__ char pls[8][2048];   // per-wave P (16q x 64s) in A-frag order
  __shared__ int mzf;             // 1 if any pad-mask zero for this b

  const int tid = threadIdx.x;
  const int wid = tid >> 6, lane = tid & 63;
  const int lm = lane & 15, lq = lane >> 4;
  const int bid = blockIdx.x;
  const int bh_i = bid & 63;
  const int qt = 15 - (bid >> 6);         // descending work order
  const int b = bh_i >> 4, h = bh_i & 15;
  const int mf = *mfp;
  const size_t bh = (size_t)(b * NH + h);
  const u16* Qbh = Qh + bh * T_SEQ * DH;
  const u16* Kbh = Kh + bh * T_SEQ * DH;
  const u16* VTbh = VTh + bh * DH * T_SEQ;
  const float* amb = attn_mask + (size_t)b * T_SEQ;

  f16x8 onev;
#pragma unroll
  for (int i = 0; i < 8; ++i) onev[i] = (_Float16)1.0f;

  if (tid == 0) mzf = 0;
  __syncthreads();
  {
    int az = 0;
    for (int i = tid; i < T_SEQ; i += 512) az |= (amb[i] == 0.0f);
    if (az) mzf = 1;  // benign same-value race
  }
  __syncthreads();
  const int maskzero = mzf;

  const int qw = qt * 128 + wid * 16;
  f16x8 qf[2];
  qf[0] = *(const f16x8*)(Qbh + (size_t)(qw + lm) * DH + lq * 8);
  qf[1] = *(const f16x8*)(Qbh + (size_t)(qw + lm) * DH + 32 + lq * 8);

  f32x4 acc[4] = {};
  f32x4 accs = {};                 // row-sum accumulator: accs[r] = lsum(q=lq*4+r)
  float mprev = -1e30f;

  const int nch = mf ? (qt + 1) * 2 : 32;
  {
    async_load16(Kbh + (size_t)((wid >> 1) * 16 + lm) * DH + (wid & 1) * 32 + lq * 8,
                 kls[0] + wid * 1024);
    async_load16(VTbh + (size_t)((wid >> 1) * 16 + lm) * T_SEQ + (wid & 1) * 32 + lq * 8,
                 vls[0] + wid * 1024);
  }
  for (int c = 0; c < nch; ++c) {
    const int s0 = c * 64;
    asm volatile("s_waitcnt vmcnt(0)" ::: "memory");
    __builtin_amdgcn_s_barrier();
    asm volatile("" ::: "memory");
    if (c + 1 < nch) {
      const int s1 = s0 + 64;
      async_load16(Kbh + (size_t)(s1 + (wid >> 1) * 16 + lm) * DH + (wid & 1) * 32 + lq * 8,
                   kls[(c + 1) & 1] + wid * 1024);
      async_load16(VTbh + (size_t)((wid >> 1) * 16 + lm) * T_SEQ + s1 + (wid & 1) * 32 + lq * 8,
                   vls[(c + 1) & 1] + wid * 1024);
    }
    const char* kcur = kls[c & 1];
    const char* vcur = vls[c & 1];

    f32x4 sc[4];
    for (int st = 0; st < 4; ++st) {
      f32x4 z = {0.f, 0.f, 0.f, 0.f};
      sc[st] = z;
      for (int kk = 0; kk < 2; ++kk) {
        f16x8 kf = *(const f16x8*)(kcur + ((st * 2 + kk) * 64 + lane) * 16);
        sc[st] = __builtin_amdgcn_mfma_f32_16x16x32_f16(kf, qf[kk], sc[st], 0, 0, 0);
      }
    }
    if (maskzero) {  // rare path: pad bias straight from global (L2-resident)
      for (int st = 0; st < 4; ++st) {
        f32x4 mb = *(const f32x4*)(amb + s0 + st * 16 + lq * 4);
        for (int r = 0; r < 4; ++r)
          if (mb[r] == 0.0f) sc[st][r] += NEG2;
      }
    }
    if (mf && (s0 + 64 > qw)) {
      int qg = qw + lm;
      for (int st = 0; st < 4; ++st)
        for (int r = 0; r < 4; ++r)
          if (s0 + st * 16 + lq * 4 + r > qg) sc[st][r] = NEG2;
    }
    // chunk max via max3-shaped tree (8 ops)
    float u0 = fmaxf(fmaxf(sc[0][0], sc[0][1]), sc[0][2]);
    float u1 = fmaxf(fmaxf(sc[0][3], sc[1][0]), sc[1][1]);
    float u2 = fmaxf(fmaxf(sc[1][2], sc[1][3]), sc[2][0]);
    float u3 = fmaxf(fmaxf(sc[2][1], sc[2][2]), sc[2][3]);
    float u4 = fmaxf(fmaxf(sc[3][0], sc[3][1]), sc[3][2]);
    float mx = fmaxf(fmaxf(fmaxf(u0, u1), u2), fmaxf(fmaxf(u3, u4), sc[3][3]));
    mx = fmaxf(mx, __shfl_xor(mx, 16));
    mx = fmaxf(mx, __shfl_xor(mx, 32));
    // defer-max: rescale only when the max grew by more than THR=8 (log2 domain)
    if (__ballot(mx > mprev + 8.0f) != 0ull) {
      float mn2 = fmaxf(mprev, mx);
      float alpha = exp2f(mprev - mn2);
      for (int r = 0; r < 4; ++r) {
        float ar = __shfl(alpha, lq * 4 + r);
        for (int nt = 0; nt < 4; ++nt) acc[nt][r] *= ar;
        accs[r] *= ar;
      }
      mprev = mn2;
    }
    for (int st = 0; st < 4; ++st)
      for (int r = 0; r < 4; ++r)
        sc[st][r] = exp2f(sc[st][r] - mprev);
    {
      char* pw = pls[wid];
      for (int st = 0; st < 4; ++st) {
        int kk = st >> 1;
        int lqp = (st & 1) * 2 + (lq >> 1);
        uint2 pv;
        pv.x = pk2(sc[st][0], sc[st][1]);
        pv.y = pk2(sc[st][2], sc[st][3]);
        *(uint2*)(pw + kk * 1024 + (lqp * 16 + lm) * 16 + (lq & 1) * 8) = pv;
      }
    }
    asm volatile("s_waitcnt lgkmcnt(0)" ::: "memory");
    for (int kk = 0; kk < 2; ++kk) {
      f16x8 pf = *(const f16x8*)(pls[wid] + kk * 1024 + lane * 16);
      for (int nt = 0; nt < 4; ++nt) {
        f16x8 vf = *(const f16x8*)(vcur + ((nt * 2 + kk) * 64 + lane) * 16);
        acc[nt] = __builtin_amdgcn_mfma_f32_16x16x32_f16(pf, vf, acc[nt], 0, 0, 0);
      }
      accs = __builtin_amdgcn_mfma_f32_16x16x32_f16(pf, onev, accs, 0, 0, 0);
    }
  }
  // epilogue: accs[r] holds lsum for q=qw+lq*4+r (same row layout as acc)
  for (int r = 0; r < 4; ++r) {
    float ir = 1.0f / accs[r];
    int t = qw + lq * 4 + r;
    for (int nt = 0; nt < 4; ++nt)
      ctx[((size_t)(b * T_SEQ + t) * DM) + h * DH + nt * 16 + lm] = f2h(acc[nt][r] * ir);
  }
}

extern "C" void kernel_launch(void* const* d_in, const int* in_sizes, int n_in,
                              void* d_out, int out_size, void* d_ws, size_t ws_size,
                              hipStream_t stream) {
  const float* q = (const float*)d_in[0];
  const float* k = (const float*)d_in[1];
  const float* v = (const float*)d_in[2];
  const float* attn_mask = (const float*)d_in[3];
  const float* Wq = (const float*)d_in[4];
  const float* Wk = (const float*)d_in[5];
  const float* Wv = (const float*)d_in[6];
  const float* Wo = (const float*)d_in[7];
  const int* mf = (const int*)d_in[8];

  u16* ws = (u16*)d_ws;
  u16* qb  = ws;                      // f16 inputs [8192,1024] x3 (q,k,v contiguous)
  u16* wqb = ws + 3u * 8388608u;      // f16 weights x4
  u16* wkb = wqb + 1048576u;
  u16* wvb = wkb + 1048576u;
  u16* wob = wvb + 1048576u;
  u16* Qh  = wob + 1048576u;          // [bh][t][64]
  u16* Kh  = Qh + 8388608u;           // [bh][t][64]
  u16* VTh = Kh + 8388608u;           // [bh][dh][2048]
  u16* ctxb = ws;                     // alias over qb (dead after projections)

  convert_all<<<14336, 256, 0, stream>>>(q, k, v, Wq, Wk, Wv, Wo, qb, wqb);

  dim3 gq(32, 24);
  gemm_qkv<<<gq, 512, 0, stream>>>(qb, wqb, wkb, wvb, Qh, Kh, VTh);

  attn_kernel<<<1024, 512, 0, stream>>>(Qh, Kh, VTh, attn_mask, mf, ctxb);

  dim3 gg(32, 8);
  gemm_out<<<gg, 512, 0, stream>>>(ctxb, wob, (float*)d_out);
}

// Round 10
// 327.964 us; speedup vs baseline: 1.1303x; 1.0110x over previous
//
#include <hip/hip_runtime.h>

typedef unsigned short u16;
typedef __attribute__((ext_vector_type(8))) _Float16 f16x8;
typedef __attribute__((ext_vector_type(2))) __fp16 fp16v2;
typedef __attribute__((ext_vector_type(4))) float f32x4;
typedef __attribute__((ext_vector_type(16))) float f32x16;

#define T_SEQ 2048
#define NH 16
#define DH 64
#define DM 1024
// NEG * log2(e), masks applied in log2 domain (softmax via exp2)
#define NEG2 (-14426.95f)
// 64^-0.25 * sqrt(log2(e)) : folded so S^T comes out pre-scaled for exp2
#define QS2 (0.42466089f)

__device__ __forceinline__ unsigned pk2(float a, float b) {
  union { fp16v2 v; unsigned u; } c;
  c.v = __builtin_amdgcn_cvt_pkrtz(a, b);
  return c.u;
}
__device__ __forceinline__ u16 f2h(float a) {
  union { _Float16 h; u16 u; } c; c.h = (_Float16)a; return c.u;
}

__device__ __forceinline__ void async_load16(const void* g, void* l) {
  __builtin_amdgcn_global_load_lds(
      (const __attribute__((address_space(1))) unsigned int*)(g),
      (__attribute__((address_space(3))) unsigned int*)(l), 16, 0, 0);
}

// ---------------- convert fp32 -> fp16 ----------------
__global__ __launch_bounds__(256) void convert_all(
    const float* __restrict__ q, const float* __restrict__ k, const float* __restrict__ v,
    const float* __restrict__ Wq, const float* __restrict__ Wk, const float* __restrict__ Wv,
    const float* __restrict__ Wo, u16* __restrict__ xb, u16* __restrict__ wb) {
  int blk = blockIdx.x;
  const float* src; u16* dst;
  if (blk < 12288) {
    int s = blk >> 12;
    src = (s == 0) ? q : (s == 1) ? k : v;
    dst = xb + (size_t)s * 8388608u;
    blk &= 4095;
  } else {
    int s = (blk - 12288) >> 9;
    src = (s == 0) ? Wq : (s == 1) ? Wk : (s == 2) ? Wv : Wo;
    dst = wb + (size_t)s * 1048576u;
    blk = (blk - 12288) & 511;
  }
  size_t base = (size_t)blk * 2048 + (size_t)threadIdx.x * 8;
  float4 a = *(const float4*)(src + base);
  float4 b2 = *(const float4*)(src + base + 4);
  uint4 st;
  st.x = pk2(a.x, a.y); st.y = pk2(a.z, a.w);
  st.z = pk2(b2.x, b2.y); st.w = pk2(b2.z, b2.w);
  *(uint4*)(dst + base) = st;
}

// ---------------- fused QKV projection GEMM: 256x128 tile, BK=32, 2 blocks/CU ----
// (unchanged from round 9 -- passing)
__global__ __launch_bounds__(512) void gemm_qkv(const u16* __restrict__ A,
                                                const u16* __restrict__ Wqb,
                                                const u16* __restrict__ Wkb,
                                                const u16* __restrict__ Wvb,
                                                u16* __restrict__ Qh, u16* __restrict__ Kh,
                                                u16* __restrict__ VTh) {
  __shared__ char lds[73728];  // 3 x 24KB staging; epilogue tile aliases [0, ~68KB)
  const int tid = threadIdx.x;
  const int wid = tid >> 6, lane = tid & 63;
  const int l32 = lane & 31, lh = lane >> 5;
  const int m0 = blockIdx.x * 256;               // t rows
  const int n0 = blockIdx.y * 128;               // ch cols + which
  const int which = n0 >> 10;
  const int n0l = n0 & 1023;
  const u16* As = A + (size_t)which * 8388608u;
  const u16* Bw = (which == 0) ? Wqb : (which == 1) ? Wkb : Wvb;
  f32x16 acc[2][2] = {};

  const u16* gsrc[3]; int ldso[3];
#pragma unroll
  for (int u = 0; u < 3; ++u) {
    int c = wid * 3 + u;
    ldso[u] = c * 1024;
    if (c < 16)
      gsrc[u] = As + (size_t)(m0 + (c >> 1) * 32 + l32) * 1024 + (c & 1) * 16 + lh * 8;
    else {
      int cw = c - 16;
      gsrc[u] = Bw + (size_t)(n0l + (cw >> 1) * 32 + l32) * 1024 + (cw & 1) * 16 + lh * 8;
    }
  }

  const int rOff = (which < 2) ? 16384 : 0;   // Q/K: rows = W; V: rows = X
  const int cOff = 16384 - rOff;
  const int rgo = (which < 2) ? ((wid & 1) * 2) : ((wid >> 1) * 2);
  const int cgo = (which < 2) ? ((wid >> 1) * 2) : ((wid & 1) * 2);

#pragma unroll
  for (int u = 0; u < 3; ++u) async_load16(gsrc[u] + 0 * 32, lds + 0 * 24576 + ldso[u]);
#pragma unroll
  for (int u = 0; u < 3; ++u) async_load16(gsrc[u] + 1 * 32, lds + 1 * 24576 + ldso[u]);

  int slotc = 0, slotn = 2;
  for (int kt = 0; kt < 32; ++kt) {
    if (kt < 31) asm volatile("s_waitcnt vmcnt(3)" ::: "memory");
    else         asm volatile("s_waitcnt vmcnt(0)" ::: "memory");
    __builtin_amdgcn_s_barrier();   // all waves' tile-kt loads landed; buf (kt+2)%3 free
    asm volatile("" ::: "memory");  // pin LDS ops below the barrier
    char* bufc = lds + slotc * 24576;
    if (kt < 30) {
      char* bufn = lds + slotn * 24576;
      int ko = (kt + 2) * 32;
#pragma unroll
      for (int u = 0; u < 3; ++u) async_load16(gsrc[u] + ko, bufn + ldso[u]);
    }
    const char* rb = bufc + rOff;
    const char* cb = bufc + cOff;
    f16x8 r0[2], c0[2], r1[2], c1[2];
#pragma unroll
    for (int i = 0; i < 2; ++i) {
      r0[i] = *(const f16x8*)(rb + ((rgo + i) * 2 + 0) * 1024 + lane * 16);
      c0[i] = *(const f16x8*)(cb + ((cgo + i) * 2 + 0) * 1024 + lane * 16);
    }
#pragma unroll
    for (int i = 0; i < 2; ++i) {
      r1[i] = *(const f16x8*)(rb + ((rgo + i) * 2 + 1) * 1024 + lane * 16);
      c1[i] = *(const f16x8*)(cb + ((cgo + i) * 2 + 1) * 1024 + lane * 16);
    }
    __builtin_amdgcn_s_setprio(1);
#pragma unroll
    for (int i = 0; i < 2; ++i)
#pragma unroll
      for (int j = 0; j < 2; ++j)
        acc[i][j] = __builtin_amdgcn_mfma_f32_32x32x16_f16(r0[i], c0[j], acc[i][j], 0, 0, 0);
#pragma unroll
    for (int i = 0; i < 2; ++i)
#pragma unroll
      for (int j = 0; j < 2; ++j)
        acc[i][j] = __builtin_amdgcn_mfma_f32_32x32x16_f16(r1[i], c1[j], acc[i][j], 0, 0, 0);
    __builtin_amdgcn_s_setprio(0);
    slotc = (slotc == 2) ? 0 : slotc + 1;
    slotn = (slotn == 2) ? 0 : slotn + 1;
  }

  // epilogue. C/D 32x32: col = l32, row = (reg&3)+8*(reg>>2)+4*lh. (unchanged)
  const float s = (which < 2) ? QS2 : 1.0f;
  const int b = m0 >> 11, t0 = m0 & 2047, h0 = n0l >> 6;
  __syncthreads();  // full drain before aliasing staging LDS
  if (which < 2) {
#pragma unroll
    for (int i = 0; i < 2; ++i)
#pragma unroll
      for (int j = 0; j < 2; ++j) {
        int colb = (wid >> 1) * 64 + j * 32 + l32;   // t_local
        int rowb = (wid & 1) * 64 + i * 32 + 4 * lh; // ch base
#pragma unroll
        for (int g = 0; g < 4; ++g) {
          uint2 pv;
          pv.x = pk2(acc[i][j][4 * g + 0] * s, acc[i][j][4 * g + 1] * s);
          pv.y = pk2(acc[i][j][4 * g + 2] * s, acc[i][j][4 * g + 3] * s);
          *(uint2*)(lds + colb * 264 + (rowb + 8 * g) * 2) = pv;
        }
      }
    __syncthreads();
    u16* O = which ? Kh : Qh;
#pragma unroll
    for (int p = 0; p < 8; ++p) {
      int row = p * 32 + (tid >> 4);  // t_local 0..255
      int seg = tid & 15;
      uint4 val = *(const uint4*)(lds + row * 264 + seg * 16);
      int hl = seg >> 3, dh0 = (seg & 7) * 8;
      *(uint4*)(O + (((size_t)(b * NH + h0 + hl) * T_SEQ + t0 + row) << 6) + dh0) = val;
    }
  } else {
#pragma unroll
    for (int i = 0; i < 2; ++i)
#pragma unroll
      for (int j = 0; j < 2; ++j) {
        int colb = (wid & 1) * 64 + j * 32 + l32;    // ch_local
        int rowb = (wid >> 1) * 64 + i * 32 + 4 * lh; // t base
#pragma unroll
        for (int g = 0; g < 4; ++g) {
          uint2 pv;
          pv.x = pk2(acc[i][j][4 * g + 0], acc[i][j][4 * g + 1]);
          pv.y = pk2(acc[i][j][4 * g + 2], acc[i][j][4 * g + 3]);
          *(uint2*)(lds + colb * 520 + (rowb + 8 * g) * 2) = pv;
        }
      }
    __syncthreads();
#pragma unroll
    for (int p = 0; p < 8; ++p) {
      int row = p * 16 + (tid >> 5);  // ch_local 0..127
      int seg = tid & 31;
      uint4 val = *(const uint4*)(lds + row * 520 + seg * 16);
      int h = h0 + (row >> 6), dh = row & 63;
      *(uint4*)(VTh + (((size_t)(b * NH + h) * DH + dh) << 11) + t0 + seg * 8) = val;
    }
  }
}

// ---------------- output projection GEMM: same 256x128/BK=32 single-barrier template ----
// (unchanged from round 9 -- passing)
__global__ __launch_bounds__(512) void gemm_out(const u16* __restrict__ A,
                                                const u16* __restrict__ Bw,
                                                float* __restrict__ O) {
  __shared__ char lds[73728];
  const int tid = threadIdx.x;
  const int wid = tid >> 6, lane = tid & 63;
  const int l32 = lane & 31, lh = lane >> 5;
  const int m0 = blockIdx.x * 256, n0 = blockIdx.y * 128;
  f32x16 acc[2][2] = {};

  const u16* gsrc[3]; int ldso[3];
#pragma unroll
  for (int u = 0; u < 3; ++u) {
    int c = wid * 3 + u;
    ldso[u] = c * 1024;
    if (c < 16)
      gsrc[u] = A + (size_t)(m0 + (c >> 1) * 32 + l32) * 1024 + (c & 1) * 16 + lh * 8;
    else {
      int cw = c - 16;
      gsrc[u] = Bw + (size_t)(n0 + (cw >> 1) * 32 + l32) * 1024 + (cw & 1) * 16 + lh * 8;
    }
  }
  const int rgo = (wid >> 1) * 2, cgo = (wid & 1) * 2;

#pragma unroll
  for (int u = 0; u < 3; ++u) async_load16(gsrc[u] + 0 * 32, lds + 0 * 24576 + ldso[u]);
#pragma unroll
  for (int u = 0; u < 3; ++u) async_load16(gsrc[u] + 1 * 32, lds + 1 * 24576 + ldso[u]);

  int slotc = 0, slotn = 2;
  for (int kt = 0; kt < 32; ++kt) {
    if (kt < 31) asm volatile("s_waitcnt vmcnt(3)" ::: "memory");
    else         asm volatile("s_waitcnt vmcnt(0)" ::: "memory");
    __builtin_amdgcn_s_barrier();
    asm volatile("" ::: "memory");
    char* bufc = lds + slotc * 24576;
    if (kt < 30) {
      char* bufn = lds + slotn * 24576;
      int ko = (kt + 2) * 32;
#pragma unroll
      for (int u = 0; u < 3; ++u) async_load16(gsrc[u] + ko, bufn + ldso[u]);
    }
    const char* rb = bufc;           // X region (rows = t)
    const char* cb = bufc + 16384;   // W region (rows = e)
    f16x8 r0[2], c0[2], r1[2], c1[2];
#pragma unroll
    for (int i = 0; i < 2; ++i) {
      r0[i] = *(const f16x8*)(rb + ((rgo + i) * 2 + 0) * 1024 + lane * 16);
      c0[i] = *(const f16x8*)(cb + ((cgo + i) * 2 + 0) * 1024 + lane * 16);
    }
#pragma unroll
    for (int i = 0; i < 2; ++i) {
      r1[i] = *(const f16x8*)(rb + ((rgo + i) * 2 + 1) * 1024 + lane * 16);
      c1[i] = *(const f16x8*)(cb + ((cgo + i) * 2 + 1) * 1024 + lane * 16);
    }
    __builtin_amdgcn_s_setprio(1);
#pragma unroll
    for (int i = 0; i < 2; ++i)
#pragma unroll
      for (int j = 0; j < 2; ++j)
        acc[i][j] = __builtin_amdgcn_mfma_f32_32x32x16_f16(r0[i], c0[j], acc[i][j], 0, 0, 0);
#pragma unroll
    for (int i = 0; i < 2; ++i)
#pragma unroll
      for (int j = 0; j < 2; ++j)
        acc[i][j] = __builtin_amdgcn_mfma_f32_32x32x16_f16(r1[i], c1[j], acc[i][j], 0, 0, 0);
    __builtin_amdgcn_s_setprio(0);
    slotc = (slotc == 2) ? 0 : slotc + 1;
    slotn = (slotn == 2) ? 0 : slotn + 1;
  }
  // epilogue: direct fp32 stores. row = rowb + 8*g + rr, col contiguous over l32.
#pragma unroll
  for (int i = 0; i < 2; ++i)
#pragma unroll
    for (int j = 0; j < 2; ++j) {
      int col = n0 + (wid & 1) * 64 + j * 32 + l32;
      int rowb = m0 + (wid >> 1) * 64 + i * 32 + 4 * lh;
#pragma unroll
      for (int g = 0; g < 4; ++g)
#pragma unroll
        for (int rr = 0; rr < 4; ++rr)
          O[(size_t)(rowb + 8 * g + rr) * 1024 + col] = acc[i][j][4 * g + rr];
    }
}

// ---------------- Flash attention (S^T formulation, fp16, 8 waves) ----------------
// Round-10 changes (LDS diet -> 4 blocks/CU; math identical to passing r9):
//  - V single-buffered: V(c) load issued at top of chunk c (after the barrier),
//    consumed at PV ~1000+ cyc later -> L2 latency fully hidden. K keeps dbuf
//    (needed immediately at chunk start). vmcnt: V issued BEFORE K(c+1), so
//    vmcnt(1) before PV waits V while K(c+1) stays in flight; top-of-loop
//    vmcnt(0) waits only K(c) (sole outstanding).
//  - pls halved to 1KB/wave: P cell reused across kk halves (write st0,1 ->
//    pf read -> PV kk0 -> write st2,3 -> pf -> PV kk1). Same-wave DS ops are
//    program-ordered through the aliasing load/store, so no extra sync.
// LDS total ~32.8KB -> 4 blocks/CU; grid 1024 = exactly 4/CU, one round.
__global__ __launch_bounds__(512) void attn_kernel(const u16* __restrict__ Qh,
                                                   const u16* __restrict__ Kh,
                                                   const u16* __restrict__ VTh,
                                                   const float* __restrict__ attn_mask,
                                                   const int* __restrict__ mfp,
                                                   u16* __restrict__ ctx) {
  __shared__ char kls[2][8192];   // K chunk (64s x 64k), cells (st*2+kk), x2 dbuf
  __shared__ char vls[8192];      // V^T chunk (64dh x 64s), cells (nt*2+kk), single
  __shared__ char pls[8][1024];   // per-wave P (16q x 32s) in A-frag order, kk-phased
  __shared__ int mzf;             // 1 if any pad-mask zero for this b

  const int tid = threadIdx.x;
  const int wid = tid >> 6, lane = tid & 63;
  const int lm = lane & 15, lq = lane >> 4;
  const int bid = blockIdx.x;
  const int bh_i = bid & 63;
  const int qt = 15 - (bid >> 6);         // descending work order
  const int b = bh_i >> 4, h = bh_i & 15;
  const int mf = *mfp;
  const size_t bh = (size_t)(b * NH + h);
  const u16* Qbh = Qh + bh * T_SEQ * DH;
  const u16* Kbh = Kh + bh * T_SEQ * DH;
  const u16* VTbh = VTh + bh * DH * T_SEQ;
  const float* amb = attn_mask + (size_t)b * T_SEQ;

  f16x8 onev;
#pragma unroll
  for (int i = 0; i < 8; ++i) onev[i] = (_Float16)1.0f;

  if (tid == 0) mzf = 0;
  __syncthreads();
  {
    int az = 0;
    for (int i = tid; i < T_SEQ; i += 512) az |= (amb[i] == 0.0f);
    if (az) mzf = 1;  // benign same-value race
  }
  __syncthreads();
  const int maskzero = mzf;

  const int qw = qt * 128 + wid * 16;
  f16x8 qf[2];
  qf[0] = *(const f16x8*)(Qbh + (size_t)(qw + lm) * DH + lq * 8);
  qf[1] = *(const f16x8*)(Qbh + (size_t)(qw + lm) * DH + 32 + lq * 8);

  f32x4 acc[4] = {};
  f32x4 accs = {};                 // row-sum accumulator: accs[r] = lsum(q=lq*4+r)
  float mprev = -1e30f;

  const int nch = mf ? (qt + 1) * 2 : 32;
  // prologue: issue K(0) only (V is loaded per-chunk)
  async_load16(Kbh + (size_t)((wid >> 1) * 16 + lm) * DH + (wid & 1) * 32 + lq * 8,
               kls[0] + wid * 1024);

  for (int c = 0; c < nch; ++c) {
    const int s0 = c * 64;
    asm volatile("s_waitcnt vmcnt(0)" ::: "memory");  // K(c) landed (sole outstanding)
    __builtin_amdgcn_s_barrier();   // all waves' K(c) landed; vls free (PV(c-1) done)
    asm volatile("" ::: "memory");
    // V(c) first (older in vmcnt order), then K(c+1)
    async_load16(VTbh + (size_t)((wid >> 1) * 16 + lm) * T_SEQ + s0 + (wid & 1) * 32 + lq * 8,
                 vls + wid * 1024);
    if (c + 1 < nch) {
      async_load16(Kbh + (size_t)(s0 + 64 + (wid >> 1) * 16 + lm) * DH + (wid & 1) * 32 + lq * 8,
                   kls[(c + 1) & 1] + wid * 1024);
    }
    const char* kcur = kls[c & 1];

    f32x4 sc[4];
    for (int st = 0; st < 4; ++st) {
      f32x4 z = {0.f, 0.f, 0.f, 0.f};
      sc[st] = z;
      for (int kk = 0; kk < 2; ++kk) {
        f16x8 kf = *(const f16x8*)(kcur + ((st * 2 + kk) * 64 + lane) * 16);
        sc[st] = __builtin_amdgcn_mfma_f32_16x16x32_f16(kf, qf[kk], sc[st], 0, 0, 0);
      }
    }
    if (maskzero) {  // rare path: pad bias straight from global (L2-resident)
      for (int st = 0; st < 4; ++st) {
        f32x4 mb = *(const f32x4*)(amb + s0 + st * 16 + lq * 4);
        for (int r = 0; r < 4; ++r)
          if (mb[r] == 0.0f) sc[st][r] += NEG2;
      }
    }
    if (mf && (s0 + 64 > qw)) {
      int qg = qw + lm;
      for (int st = 0; st < 4; ++st)
        for (int r = 0; r < 4; ++r)
          if (s0 + st * 16 + lq * 4 + r > qg) sc[st][r] = NEG2;
    }
    // chunk max via max3-shaped tree (8 ops)
    float u0 = fmaxf(fmaxf(sc[0][0], sc[0][1]), sc[0][2]);
    float u1 = fmaxf(fmaxf(sc[0][3], sc[1][0]), sc[1][1]);
    float u2 = fmaxf(fmaxf(sc[1][2], sc[1][3]), sc[2][0]);
    float u3 = fmaxf(fmaxf(sc[2][1], sc[2][2]), sc[2][3]);
    float u4 = fmaxf(fmaxf(sc[3][0], sc[3][1]), sc[3][2]);
    float mx = fmaxf(fmaxf(fmaxf(u0, u1), u2), fmaxf(fmaxf(u3, u4), sc[3][3]));
    mx = fmaxf(mx, __shfl_xor(mx, 16));
    mx = fmaxf(mx, __shfl_xor(mx, 32));
    // defer-max: rescale only when the max grew by more than THR=8 (log2 domain)
    if (__ballot(mx > mprev + 8.0f) != 0ull) {
      float mn2 = fmaxf(mprev, mx);
      float alpha = exp2f(mprev - mn2);
      for (int r = 0; r < 4; ++r) {
        float ar = __shfl(alpha, lq * 4 + r);
        for (int nt = 0; nt < 4; ++nt) acc[nt][r] *= ar;
        accs[r] *= ar;
      }
      mprev = mn2;
    }
    for (int st = 0; st < 4; ++st)
      for (int r = 0; r < 4; ++r)
        sc[st][r] = exp2f(sc[st][r] - mprev);

    // ---- kk=0: P write (st 0,1) -> PV kk0 ----
    {
      char* pw = pls[wid];
      for (int st = 0; st < 2; ++st) {
        int lqp = (st & 1) * 2 + (lq >> 1);
        uint2 pv;
        pv.x = pk2(sc[st][0], sc[st][1]);
        pv.y = pk2(sc[st][2], sc[st][3]);
        *(uint2*)(pw + (lqp * 16 + lm) * 16 + (lq & 1) * 8) = pv;
      }
    }
    // V(c) landed; K(c+1) (newest) may stay in flight
    if (c + 1 < nch) asm volatile("s_waitcnt vmcnt(1)" ::: "memory");
    else             asm volatile("s_waitcnt vmcnt(0)" ::: "memory");
    asm volatile("s_waitcnt lgkmcnt(0)" ::: "memory");
    {
      f16x8 pf = *(const f16x8*)(pls[wid] + lane * 16);
      for (int nt = 0; nt < 4; ++nt) {
        f16x8 vf = *(const f16x8*)(vls + ((nt * 2 + 0) * 64 + lane) * 16);
        acc[nt] = __builtin_amdgcn_mfma_f32_16x16x32_f16(pf, vf, acc[nt], 0, 0, 0);
      }
      accs = __builtin_amdgcn_mfma_f32_16x16x32_f16(pf, onev, accs, 0, 0, 0);
    }
    // ---- kk=1: P write (st 2,3) -> PV kk1 (same pls cell; same-wave DS order) ----
    {
      char* pw = pls[wid];
      for (int st = 2; st < 4; ++st) {
        int lqp = (st & 1) * 2 + (lq >> 1);
        uint2 pv;
        pv.x = pk2(sc[st][0], sc[st][1]);
        pv.y = pk2(sc[st][2], sc[st][3]);
        *(uint2*)(pw + (lqp * 16 + lm) * 16 + (lq & 1) * 8) = pv;
      }
    }
    asm volatile("s_waitcnt lgkmcnt(0)" ::: "memory");
    {
      f16x8 pf = *(const f16x8*)(pls[wid] + lane * 16);
      for (int nt = 0; nt < 4; ++nt) {
        f16x8 vf = *(const f16x8*)(vls + ((nt * 2 + 1) * 64 + lane) * 16);
        acc[nt] = __builtin_amdgcn_mfma_f32_16x16x32_f16(pf, vf, acc[nt], 0, 0, 0);
      }
      accs = __builtin_amdgcn_mfma_f32_16x16x32_f16(pf, onev, accs, 0, 0, 0);
    }
  }
  // epilogue: accs[r] holds lsum for q=qw+lq*4+r (same row layout as acc)
  for (int r = 0; r < 4; ++r) {
    float ir = 1.0f / accs[r];
    int t = qw + lq * 4 + r;
    for (int nt = 0; nt < 4; ++nt)
      ctx[((size_t)(b * T_SEQ + t) * DM) + h * DH + nt * 16 + lm] = f2h(acc[nt][r] * ir);
  }
}

extern "C" void kernel_launch(void* const* d_in, const int* in_sizes, int n_in,
                              void* d_out, int out_size, void* d_ws, size_t ws_size,
                              hipStream_t stream) {
  const float* q = (const float*)d_in[0];
  const float* k = (const float*)d_in[1];
  const float* v = (const float*)d_in[2];
  const float* attn_mask = (const float*)d_in[3];
  const float* Wq = (const float*)d_in[4];
  const float* Wk = (const float*)d_in[5];
  const float* Wv = (const float*)d_in[6];
  const float* Wo = (const float*)d_in[7];
  const int* mf = (const int*)d_in[8];

  u16* ws = (u16*)d_ws;
  u16* qb  = ws;                      // f16 inputs [8192,1024] x3 (q,k,v contiguous)
  u16* wqb = ws + 3u * 8388608u;      // f16 weights x4
  u16* wkb = wqb + 1048576u;
  u16* wvb = wkb + 1048576u;
  u16* wob = wvb + 1048576u;
  u16* Qh  = wob + 1048576u;          // [bh][t][64]
  u16* Kh  = Qh + 8388608u;           // [bh][t][64]
  u16* VTh = Kh + 8388608u;           // [bh][dh][2048]
  u16* ctxb = ws;                     // alias over qb (dead after projections)

  convert_all<<<14336, 256, 0, stream>>>(q, k, v, Wq, Wk, Wv, Wo, qb, wqb);

  dim3 gq(32, 24);
  gemm_qkv<<<gq, 512, 0, stream>>>(qb, wqb, wkb, wvb, Qh, Kh, VTh);

  attn_kernel<<<1024, 512, 0, stream>>>(Qh, Kh, VTh, attn_mask, mf, ctxb);

  dim3 gg(32, 8);
  gemm_out<<<gg, 512, 0, stream>>>(ctxb, wob, (float*)d_out);
}